// Round 7
// baseline (542.099 us; speedup 1.0000x reference)
//
#include <hip/hip_runtime.h>
#include <hip/hip_bf16.h>
#include <math.h>

// GCN forward: 4 GraphConv layers + sum-pool + FC head + softmax.
// N_NODES=100000, N_EDGES=3200000, N_GRAPHS=64, IN=128, DIM=32.
//
// Round-7:
//  - A (neighbor-transform) stored as fp8 e4m3fn: 3.2 MB table fits a 4 MB
//    per-XCD L2 -> gather becomes L2-resident (bf16's 6.4 MB didn't fit).
//    Accumulation fp32; self-path + bias fp32.
//  - Transform kernels: weights transposed in LDS (stride 132/36, stride/4
//    odd) -> float4 weight reads + broadcast float4 x reads; VALU-bound.

#define TILE_NODES 256
#define CE 12800                 // edges per sort chunk
#define SCAN_CHUNK 2048
#define MAX_NB 1024

// ---- fp8 e4m3fn software encode/decode (branch-free) ----
__device__ inline unsigned char f2fp8(float f) {
    unsigned u = __float_as_uint(f);
    unsigned s = (u >> 24) & 0x80u;
    float a = fminf(fabsf(f), 448.f);
    unsigned v = __float_as_uint(a * 0x1p-120f);   // e4m3 window -> f32 exp field
    v = v + 0xFFFFFu + ((v >> 20) & 1u);           // RTN-even to 3 mantissa bits
    return (unsigned char)(s | ((v >> 20) & 0x7Fu));
}
__device__ inline float fp8_dec(unsigned x) {      // x = one byte
    unsigned v = ((x & 0x80u) << 24) | ((x & 0x7Fu) << 20);
    return __uint_as_float(v) * 0x1p120f;
}
__device__ inline float4 dec4(unsigned w) {
    return make_float4(fp8_dec(w & 0xFFu), fp8_dec((w >> 8) & 0xFFu),
                       fp8_dec((w >> 16) & 0xFFu), fp8_dec((w >> 24) & 0xFFu));
}

// ---------------- Pass 1: per-chunk histogram over dst tiles ----------------
__global__ __launch_bounds__(1024) void k_hist2(
    const int* __restrict__ dst, int* __restrict__ histT,
    int n_edges, int NB, int C)
{
    __shared__ int hist[MAX_NB];
    const int c = blockIdx.x;
    for (int b = threadIdx.x; b < NB; b += 1024) hist[b] = 0;
    __syncthreads();
    const int beg = c * CE;
    const int end = min(beg + CE, n_edges);
    for (int e = beg + threadIdx.x; e < end; e += 1024)
        atomicAdd(&hist[dst[e] >> 8], 1);
    __syncthreads();
    for (int b = threadIdx.x; b < NB; b += 1024)
        histT[b * C + c] = hist[b];
}

// ---------------- Pass 2: hierarchical exclusive scan of histT ----------------
__global__ __launch_bounds__(256) void k_chunk_sum(
    const int* __restrict__ v, int* __restrict__ part, int n)
{
    __shared__ int red[256];
    const int base = blockIdx.x * SCAN_CHUNK;
    int s = 0;
    for (int i = threadIdx.x; i < SCAN_CHUNK; i += 256) {
        int idx = base + i;
        if (idx < n) s += v[idx];
    }
    red[threadIdx.x] = s;
    __syncthreads();
    for (int off = 128; off > 0; off >>= 1) {
        if (threadIdx.x < off) red[threadIdx.x] += red[threadIdx.x + off];
        __syncthreads();
    }
    if (threadIdx.x == 0) part[blockIdx.x] = red[0];
}

__global__ void k_scan_part(int* __restrict__ part, int nparts)
{
    if (threadIdx.x == 0 && blockIdx.x == 0) {
        int run = 0;
        for (int i = 0; i < nparts; ++i) { int v = part[i]; part[i] = run; run += v; }
    }
}

__global__ __launch_bounds__(256) void k_write_off(
    const int* __restrict__ v, const int* __restrict__ part,
    int* __restrict__ off, int n, int total)
{
    __shared__ int lds[256];
    const int tid   = threadIdx.x;
    const int base  = blockIdx.x * SCAN_CHUNK;
    const int tbase = base + tid * 8;
    int c[8];
    int tot = 0;
#pragma unroll
    for (int m = 0; m < 8; ++m) {
        int idx = tbase + m;
        c[m] = (idx < n) ? v[idx] : 0;
        tot += c[m];
    }
    lds[tid] = tot;
    __syncthreads();
    for (int o = 1; o < 256; o <<= 1) {
        int val = (tid >= o) ? lds[tid - o] : 0;
        __syncthreads();
        lds[tid] += val;
        __syncthreads();
    }
    int run = part[blockIdx.x] + lds[tid] - tot;
#pragma unroll
    for (int m = 0; m < 8; ++m) {
        int idx = tbase + m;
        if (idx < n) off[idx] = run;
        run += c[m];
    }
    if (blockIdx.x == 0 && tid == 0) off[n] = total;
}

// ---------------- Pass 3: bin packed edges into tile regions ----------------
__global__ __launch_bounds__(1024) void k_binfill(
    const int* __restrict__ src, const int* __restrict__ dst,
    const int* __restrict__ off, unsigned int* __restrict__ ebuf,
    int n_edges, int NB, int C)
{
    __shared__ int lcur[MAX_NB];
    const int c = blockIdx.x;
    for (int b = threadIdx.x; b < NB; b += 1024)
        lcur[b] = off[b * C + c];
    __syncthreads();
    const int beg = c * CE;
    const int end = min(beg + CE, n_edges);
    for (int e = beg + threadIdx.x; e < end; e += 1024) {
        const int d = dst[e];
        const int b = d >> 8;
        const unsigned int dl = (unsigned int)(d & 255);
        const int pos = atomicAdd(&lcur[b], 1);
        ebuf[pos] = (dl << 17) | (unsigned int)src[e];
    }
}

// ---------------- Pass 4: per-tile counting sort -> eidx + ptr ----------------
__global__ __launch_bounds__(1024) void k_tile_sort(
    const int* __restrict__ off, const unsigned int* __restrict__ ebuf,
    int* __restrict__ eidx, int* __restrict__ ptr,
    int n_nodes, int NB, int C, int n_edges)
{
    __shared__ int hist[TILE_NODES];
    __shared__ int scan[TILE_NODES];
    __shared__ int cur[TILE_NODES];
    const int t = blockIdx.x;
    const int beg = off[t * C];
    const int end = (t + 1 < NB) ? off[(t + 1) * C] : n_edges;
    const int node_base = t * TILE_NODES;
    const int n_valid = min(TILE_NODES, n_nodes - node_base);

    if (threadIdx.x < TILE_NODES) hist[threadIdx.x] = 0;
    __syncthreads();
    for (int e = beg + threadIdx.x; e < end; e += 1024)
        atomicAdd(&hist[ebuf[e] >> 17], 1);
    __syncthreads();
    if (threadIdx.x < TILE_NODES) scan[threadIdx.x] = hist[threadIdx.x];
    __syncthreads();
    for (int o = 1; o < TILE_NODES; o <<= 1) {
        int v = 0;
        if (threadIdx.x < TILE_NODES && threadIdx.x >= o) v = scan[threadIdx.x - o];
        __syncthreads();
        if (threadIdx.x < TILE_NODES) scan[threadIdx.x] += v;
        __syncthreads();
    }
    if (threadIdx.x < TILE_NODES) {
        const int ex = scan[threadIdx.x] - hist[threadIdx.x];   // exclusive
        cur[threadIdx.x] = ex;
        if (threadIdx.x < n_valid) ptr[node_base + threadIdx.x] = beg + ex;
    }
    if (t == NB - 1 && threadIdx.x == 0) ptr[n_nodes] = n_edges;
    __syncthreads();
    for (int e = beg + threadIdx.x; e < end; e += 1024) {
        const unsigned int v = ebuf[e];
        const int dl = (int)(v >> 17);
        const int pos = beg + atomicAdd(&cur[dl], 1);
        eidx[pos] = (int)(v & 0x1FFFFu);
    }
}

// ---------------- Layer 0: A(fp8) = x@Wn0 ; B = x@Ws0 + bn0 ----------------
// weights transposed in LDS: sWT[j][k], stride 132 (132/4=33 odd -> no conflict)
__global__ __launch_bounds__(256) void k_layer0(
    const float* __restrict__ x, const float* __restrict__ Wn0,
    const float* __restrict__ bn0, const float* __restrict__ Ws0,
    unsigned char* __restrict__ Ab, float* __restrict__ B, int n_nodes)
{
    __shared__ float sWnT[32 * 132];
    __shared__ float sWsT[32 * 132];
    __shared__ float sx[32 * 128];

    for (int i = threadIdx.x; i < 128 * 32; i += 256) {
        const int k = i >> 5, jj = i & 31;
        sWnT[jj * 132 + k] = Wn0[i];
        sWsT[jj * 132 + k] = Ws0[i];
    }
    const int tile = blockIdx.x * 32;
    {
        const float4* s4 = (const float4*)(x + (size_t)tile * 128);
        const int lim = (n_nodes - tile) * 32;
#pragma unroll
        for (int m = 0; m < 4; ++m) {
            int i = threadIdx.x + m * 256;
            if (i < lim) ((float4*)sx)[i] = s4[i];
        }
    }
    const int j = threadIdx.x & 31;
    const int r = threadIdx.x >> 5;
    const float bias = bn0[j];
    __syncthreads();

    float accA[4] = {0.f, 0.f, 0.f, 0.f};
    float accB[4] = {bias, bias, bias, bias};
    for (int k = 0; k < 128; k += 4) {
        const float4 wn = *(const float4*)(sWnT + j * 132 + k);
        const float4 ws = *(const float4*)(sWsT + j * 132 + k);
#pragma unroll
        for (int m = 0; m < 4; ++m) {
            const float4 xv = *(const float4*)(sx + (r + 8 * m) * 128 + k);
            accA[m] += xv.x * wn.x + xv.y * wn.y + xv.z * wn.z + xv.w * wn.w;
            accB[m] += xv.x * ws.x + xv.y * ws.y + xv.z * ws.z + xv.w * ws.w;
        }
    }
#pragma unroll
    for (int m = 0; m < 4; ++m) {
        const int node = tile + r + 8 * m;
        if (node < n_nodes) {
            Ab[(size_t)node * 32 + j] = f2fp8(accA[m]);
            B[(size_t)node * 32 + j] = accB[m];
        }
    }
}

// ------------- Layers 1..3 (in-place on B): A(fp8) = relu(B)@Wn ; B = relu(B)@Ws + bn -------------
__global__ __launch_bounds__(256) void k_layer(
    float* HB,                       // read pre-act, overwritten with new B
    const float* __restrict__ Wn, const float* __restrict__ bnv,
    const float* __restrict__ Ws, unsigned char* __restrict__ Ab, int n_nodes)
{
    __shared__ float sWnT[32 * 36];
    __shared__ float sWsT[32 * 36];
    __shared__ float sh[64 * 32];

    if (threadIdx.x < 1024 && threadIdx.x < 32 * 32) {
        // full copy handled by the strided loop below
    }
    for (int i = threadIdx.x; i < 1024; i += 256) {
        const int k = i >> 5, jj = i & 31;
        sWnT[jj * 36 + k] = Wn[i];
        sWsT[jj * 36 + k] = Ws[i];
    }
    const int tile = blockIdx.x * 64;
    {
        const float4* s4 = (const float4*)(HB + (size_t)tile * 32);
        const int lim = (n_nodes - tile) * 8;
#pragma unroll
        for (int m = 0; m < 2; ++m) {
            int i = threadIdx.x + m * 256;
            if (i < lim) {
                float4 v = s4[i];
                v.x = fmaxf(v.x, 0.f); v.y = fmaxf(v.y, 0.f);
                v.z = fmaxf(v.z, 0.f); v.w = fmaxf(v.w, 0.f);
                ((float4*)sh)[i] = v;
            }
        }
    }
    const int j = threadIdx.x & 31;
    const int r = threadIdx.x >> 5;
    const float bias = bnv[j];
    __syncthreads();

    float accA[8] = {0.f};
    float accB[8];
#pragma unroll
    for (int m = 0; m < 8; ++m) accB[m] = bias;
    for (int k = 0; k < 32; k += 4) {
        const float4 wn = *(const float4*)(sWnT + j * 36 + k);
        const float4 ws = *(const float4*)(sWsT + j * 36 + k);
#pragma unroll
        for (int m = 0; m < 8; ++m) {
            const float4 hv = *(const float4*)(sh + (r + 8 * m) * 32 + k);
            accA[m] += hv.x * wn.x + hv.y * wn.y + hv.z * wn.z + hv.w * wn.w;
            accB[m] += hv.x * ws.x + hv.y * ws.y + hv.z * ws.z + hv.w * ws.w;
        }
    }
#pragma unroll
    for (int m = 0; m < 8; ++m) {
        const int node = tile + r + 8 * m;
        if (node < n_nodes) {
            Ab[(size_t)node * 32 + j] = f2fp8(accA[m]);
            HB[(size_t)node * 32 + j] = accB[m];
        }
    }
}

// ------------- Aggregation: B[n] += sum_{e in CSR[n]} A_fp8[eidx[e]] -------------
// 2 lanes per node (uint4 = 16 fp8 each, 32B row), 8-edge unrolled batches.
__global__ __launch_bounds__(256) void k_agg2(
    const int* __restrict__ ptr, const int* __restrict__ eidx,
    const unsigned char* __restrict__ Ab, float* __restrict__ B, int n_nodes)
{
    const int g    = blockIdx.x * 128 + (threadIdx.x >> 1);
    const int lane = threadIdx.x & 1;
    if (g >= n_nodes) return;
    const int beg = ptr[g];
    const int end = ptr[g + 1];
    const uint4* __restrict__ A4 = (const uint4*)Ab;   // 16B = 16 fp8
    float4* B4 = (float4*)B;

    float4 a0 = B4[(size_t)g * 8 + lane * 4 + 0];
    float4 a1 = B4[(size_t)g * 8 + lane * 4 + 1];
    float4 a2 = B4[(size_t)g * 8 + lane * 4 + 2];
    float4 a3 = B4[(size_t)g * 8 + lane * 4 + 3];
    for (int e = beg; e < end; e += 8) {
        int idx[8];
#pragma unroll
        for (int u = 0; u < 8; ++u)
            idx[u] = (e + u < end) ? eidx[e + u] : -1;
#pragma unroll
        for (int u = 0; u < 8; ++u) {
            if (idx[u] >= 0) {
                const uint4 rw = A4[(size_t)idx[u] * 2 + lane];
                const float4 d0 = dec4(rw.x);
                const float4 d1 = dec4(rw.y);
                const float4 d2 = dec4(rw.z);
                const float4 d3 = dec4(rw.w);
                a0.x += d0.x; a0.y += d0.y; a0.z += d0.z; a0.w += d0.w;
                a1.x += d1.x; a1.y += d1.y; a1.z += d1.z; a1.w += d1.w;
                a2.x += d2.x; a2.y += d2.y; a2.z += d2.z; a2.w += d2.w;
                a3.x += d3.x; a3.y += d3.y; a3.z += d3.z; a3.w += d3.w;
            }
        }
    }
    B4[(size_t)g * 8 + lane * 4 + 0] = a0;
    B4[(size_t)g * 8 + lane * 4 + 1] = a1;
    B4[(size_t)g * 8 + lane * 4 + 2] = a2;
    B4[(size_t)g * 8 + lane * 4 + 3] = a3;
}

// ---------------- Zero hg ----------------
__global__ __launch_bounds__(256) void k_zero_f(float* __restrict__ p, int n)
{
    int i = blockIdx.x * 256 + threadIdx.x;
    if (i < n) p[i] = 0.f;
}

// ---------------- Node-parallel per-graph sum pool ----------------
__global__ __launch_bounds__(256) void k_pool1(
    const float* __restrict__ H, const int* __restrict__ gids,
    float* __restrict__ hg, int n_nodes)
{
    const int base = blockIdx.x * 128;
    const int lim  = min(base + 128, n_nodes);
    const int j = threadIdx.x & 31;
    const int r = threadIdx.x >> 5;

    int curg = -1;
    float acc = 0.f;
    for (int n = base + r; n < lim; n += 8) {
        const int g = gids[n];
        const float v = fmaxf(H[(size_t)n * 32 + j], 0.f);
        if (g != curg) {
            if (curg >= 0) atomicAdd(&hg[curg * 32 + j], acc);
            curg = g;
            acc = v;
        } else {
            acc += v;
        }
    }
    if (curg >= 0) atomicAdd(&hg[curg * 32 + j], acc);
}

// ---------------- FC head + softmax ----------------
__global__ __launch_bounds__(64) void k_head(
    const float* __restrict__ hg,
    const float* __restrict__ Wfc1, const float* __restrict__ bfc1,
    const float* __restrict__ Wout, const float* __restrict__ bout,
    float* __restrict__ out, int n_graphs)
{
    const int g = blockIdx.x * blockDim.x + threadIdx.x;
    if (g >= n_graphs) return;
    float h[32];
#pragma unroll
    for (int k = 0; k < 32; ++k) h[k] = hg[g * 32 + k];
    float z[8];
#pragma unroll
    for (int m = 0; m < 8; ++m) {
        float a = bfc1[m];
#pragma unroll
        for (int k = 0; k < 32; ++k) a += h[k] * Wfc1[k * 8 + m];
        z[m] = fmaxf(a, 0.f);
    }
    float o[4];
#pragma unroll
    for (int q = 0; q < 4; ++q) {
        float a = bout[q];
#pragma unroll
        for (int m = 0; m < 8; ++m) a += z[m] * Wout[m * 4 + q];
        o[q] = fmaxf(a, 0.f);
    }
    const float mx = fmaxf(fmaxf(o[0], o[1]), fmaxf(o[2], o[3]));
    const float e0 = expf(o[0] - mx), e1 = expf(o[1] - mx);
    const float e2 = expf(o[2] - mx), e3 = expf(o[3] - mx);
    const float inv = 1.f / (e0 + e1 + e2 + e3);
    out[g * 4 + 0] = e0 * inv;
    out[g * 4 + 1] = e1 * inv;
    out[g * 4 + 2] = e2 * inv;
    out[g * 4 + 3] = e3 * inv;
}

extern "C" void kernel_launch(void* const* d_in, const int* in_sizes, int n_in,
                              void* d_out, int out_size, void* d_ws, size_t ws_size,
                              hipStream_t stream)
{
    const float* x    = (const float*)d_in[0];
    const float* Wn0  = (const float*)d_in[1];
    const float* bn0  = (const float*)d_in[2];
    const float* Ws0  = (const float*)d_in[3];
    const float* Wn   = (const float*)d_in[4];   // [3,32,32]
    const float* bn   = (const float*)d_in[5];   // [3,32]
    const float* Ws   = (const float*)d_in[6];   // [3,32,32]
    const float* Wfc1 = (const float*)d_in[7];
    const float* bfc1 = (const float*)d_in[8];
    const float* Wout = (const float*)d_in[9];
    const float* bout = (const float*)d_in[10];
    const int*   src  = (const int*)d_in[11];
    const int*   dst  = (const int*)d_in[12];
    const int*   gids = (const int*)d_in[13];

    const int n_nodes  = in_sizes[0] / 128;
    const int n_edges  = in_sizes[11];
    const int n_graphs = out_size / 4;
    const size_t N32 = (size_t)n_nodes * 32;

    const int NB = (n_nodes + TILE_NODES - 1) / TILE_NODES;
    const int C  = (n_edges + CE - 1) / CE;
    const int n_off = NB * C;

    unsigned char* Ab = (unsigned char*)d_ws;            // [N,32] fp8 (N32 bytes)
    float* B   = (float*)(Ab + N32);                     // [N,32] fp32 (in-place)
    float* hg  = B + N32;                                // [G,32]
    int* histT = (int*)(hg + (size_t)n_graphs * 32);     // [NB*C]
    int* off   = histT + n_off;                          // [NB*C + 1]
    int* part  = off + n_off + 1;                        // [<=256]
    int* ptr   = part + 256;                             // [N+1]
    unsigned int* ebuf = (unsigned int*)(ptr + n_nodes + 1);  // [E]
    int* eidx  = (int*)(ebuf + n_edges);                 // [E]

    const int nparts = (n_off + SCAN_CHUNK - 1) / SCAN_CHUNK;

    // ---- edge sort (once per call; reused by all 4 layers) ----
    k_hist2<<<C, 1024, 0, stream>>>(dst, histT, n_edges, NB, C);
    k_chunk_sum<<<nparts, 256, 0, stream>>>(histT, part, n_off);
    k_scan_part<<<1, 64, 0, stream>>>(part, nparts);
    k_write_off<<<nparts, 256, 0, stream>>>(histT, part, off, n_off, n_edges);
    k_binfill<<<C, 1024, 0, stream>>>(src, dst, off, ebuf, n_edges, NB, C);
    k_tile_sort<<<NB, 1024, 0, stream>>>(off, ebuf, eidx, ptr, n_nodes, NB, C, n_edges);

    const int mblocks0 = (n_nodes + 31) / 32;
    const int mblocks  = (n_nodes + 63) / 64;
    const int ablocks  = (n_nodes + 127) / 128;

    // ---- Layer 0 ----
    k_layer0<<<mblocks0, 256, 0, stream>>>(x, Wn0, bn0, Ws0, Ab, B, n_nodes);
    k_agg2<<<ablocks, 256, 0, stream>>>(ptr, eidx, Ab, B, n_nodes);

    // ---- Layers 1..3 (in-place on B) ----
    for (int l = 0; l < 3; ++l) {
        k_layer<<<mblocks, 256, 0, stream>>>(B, Wn + l * 1024, bn + l * 32,
                                             Ws + l * 1024, Ab, n_nodes);
        k_agg2<<<ablocks, 256, 0, stream>>>(ptr, eidx, Ab, B, n_nodes);
    }

    // ---- Pool + head ----
    k_zero_f<<<(n_graphs * 32 + 255) / 256, 256, 0, stream>>>(hg, n_graphs * 32);
    k_pool1<<<(n_nodes + 127) / 128, 256, 0, stream>>>(B, gids, hg, n_nodes);
    k_head<<<(n_graphs + 63) / 64, 64, 0, stream>>>(hg, Wfc1, bfc1, Wout, bout,
                                                    (float*)d_out, n_graphs);
}

// Round 8
// 489.853 us; speedup vs baseline: 1.1067x; 1.1067x over previous
//
#include <hip/hip_runtime.h>
#include <hip/hip_bf16.h>
#include <math.h>

// GCN forward: 4 GraphConv layers + sum-pool + FC head + softmax.
// N_NODES=100000, N_EDGES=3200000, N_GRAPHS=64, IN=128, DIM=32.
//
// Round-8:
//  - A stored fp8 e4m3fn (3.2 MB, fully per-XCD-L2-resident; verified by
//    round-7 FETCH drop 128->51 MB).
//  - agg2: 4 lanes/node (400K threads) + HW fp8->f32 cvt (guarded builtin).
//  - transform kernels: straight weight layout (b32 reads, conflict-free;
//    round-7 transpose caused 4-way conflicts) + float4 x reads (2-way = free).

#define TILE_NODES 256
#define CE 12800                 // edges per sort chunk
#define SCAN_CHUNK 2048
#define MAX_NB 1024

// ---- fp8 e4m3fn software encode (RTN-even) ----
__device__ inline unsigned char f2fp8(float f) {
    unsigned u = __float_as_uint(f);
    unsigned s = (u >> 24) & 0x80u;
    float a = fminf(fabsf(f), 448.f);
    unsigned v = __float_as_uint(a * 0x1p-120f);   // e4m3 window -> f32 exp field
    v = v + 0xFFFFFu + ((v >> 20) & 1u);           // RTN-even to 3 mantissa bits
    return (unsigned char)(s | ((v >> 20) & 0x7Fu));
}
__device__ inline float fp8_dec(unsigned x) {      // one byte, software fallback
    unsigned v = ((x & 0x80u) << 24) | ((x & 0x7Fu) << 20);
    return __uint_as_float(v) * 0x1p120f;
}

typedef float v2f __attribute__((ext_vector_type(2)));

// accumulate 8 fp8 (two dwords) into two float4 accumulators
__device__ inline void acc8_fp8(unsigned w0, unsigned w1, float4& a0, float4& a1) {
#if __has_builtin(__builtin_amdgcn_cvt_pk_f32_fp8)
    v2f p0 = __builtin_amdgcn_cvt_pk_f32_fp8(w0, 0);
    v2f p1 = __builtin_amdgcn_cvt_pk_f32_fp8(w0, 1);
    v2f p2 = __builtin_amdgcn_cvt_pk_f32_fp8(w1, 0);
    v2f p3 = __builtin_amdgcn_cvt_pk_f32_fp8(w1, 1);
    a0.x += p0.x; a0.y += p0.y; a0.z += p1.x; a0.w += p1.y;
    a1.x += p2.x; a1.y += p2.y; a1.z += p3.x; a1.w += p3.y;
#else
    a0.x += fp8_dec(w0 & 0xFFu);         a0.y += fp8_dec((w0 >> 8) & 0xFFu);
    a0.z += fp8_dec((w0 >> 16) & 0xFFu); a0.w += fp8_dec(w0 >> 24);
    a1.x += fp8_dec(w1 & 0xFFu);         a1.y += fp8_dec((w1 >> 8) & 0xFFu);
    a1.z += fp8_dec((w1 >> 16) & 0xFFu); a1.w += fp8_dec(w1 >> 24);
#endif
}

// ---------------- Pass 1: per-chunk histogram over dst tiles ----------------
__global__ __launch_bounds__(1024) void k_hist2(
    const int* __restrict__ dst, int* __restrict__ histT,
    int n_edges, int NB, int C)
{
    __shared__ int hist[MAX_NB];
    const int c = blockIdx.x;
    for (int b = threadIdx.x; b < NB; b += 1024) hist[b] = 0;
    __syncthreads();
    const int beg = c * CE;
    const int end = min(beg + CE, n_edges);
    for (int e = beg + threadIdx.x; e < end; e += 1024)
        atomicAdd(&hist[dst[e] >> 8], 1);
    __syncthreads();
    for (int b = threadIdx.x; b < NB; b += 1024)
        histT[b * C + c] = hist[b];
}

// ---------------- Pass 2: hierarchical exclusive scan of histT ----------------
__global__ __launch_bounds__(256) void k_chunk_sum(
    const int* __restrict__ v, int* __restrict__ part, int n)
{
    __shared__ int red[256];
    const int base = blockIdx.x * SCAN_CHUNK;
    int s = 0;
    for (int i = threadIdx.x; i < SCAN_CHUNK; i += 256) {
        int idx = base + i;
        if (idx < n) s += v[idx];
    }
    red[threadIdx.x] = s;
    __syncthreads();
    for (int off = 128; off > 0; off >>= 1) {
        if (threadIdx.x < off) red[threadIdx.x] += red[threadIdx.x + off];
        __syncthreads();
    }
    if (threadIdx.x == 0) part[blockIdx.x] = red[0];
}

__global__ void k_scan_part(int* __restrict__ part, int nparts)
{
    if (threadIdx.x == 0 && blockIdx.x == 0) {
        int run = 0;
        for (int i = 0; i < nparts; ++i) { int v = part[i]; part[i] = run; run += v; }
    }
}

__global__ __launch_bounds__(256) void k_write_off(
    const int* __restrict__ v, const int* __restrict__ part,
    int* __restrict__ off, int n, int total)
{
    __shared__ int lds[256];
    const int tid   = threadIdx.x;
    const int base  = blockIdx.x * SCAN_CHUNK;
    const int tbase = base + tid * 8;
    int c[8];
    int tot = 0;
#pragma unroll
    for (int m = 0; m < 8; ++m) {
        int idx = tbase + m;
        c[m] = (idx < n) ? v[idx] : 0;
        tot += c[m];
    }
    lds[tid] = tot;
    __syncthreads();
    for (int o = 1; o < 256; o <<= 1) {
        int val = (tid >= o) ? lds[tid - o] : 0;
        __syncthreads();
        lds[tid] += val;
        __syncthreads();
    }
    int run = part[blockIdx.x] + lds[tid] - tot;
#pragma unroll
    for (int m = 0; m < 8; ++m) {
        int idx = tbase + m;
        if (idx < n) off[idx] = run;
        run += c[m];
    }
    if (blockIdx.x == 0 && tid == 0) off[n] = total;
}

// ---------------- Pass 3: bin packed edges into tile regions ----------------
__global__ __launch_bounds__(1024) void k_binfill(
    const int* __restrict__ src, const int* __restrict__ dst,
    const int* __restrict__ off, unsigned int* __restrict__ ebuf,
    int n_edges, int NB, int C)
{
    __shared__ int lcur[MAX_NB];
    const int c = blockIdx.x;
    for (int b = threadIdx.x; b < NB; b += 1024)
        lcur[b] = off[b * C + c];
    __syncthreads();
    const int beg = c * CE;
    const int end = min(beg + CE, n_edges);
    for (int e = beg + threadIdx.x; e < end; e += 1024) {
        const int d = dst[e];
        const int b = d >> 8;
        const unsigned int dl = (unsigned int)(d & 255);
        const int pos = atomicAdd(&lcur[b], 1);
        ebuf[pos] = (dl << 17) | (unsigned int)src[e];
    }
}

// ---------------- Pass 4: per-tile counting sort -> eidx + ptr ----------------
__global__ __launch_bounds__(1024) void k_tile_sort(
    const int* __restrict__ off, const unsigned int* __restrict__ ebuf,
    int* __restrict__ eidx, int* __restrict__ ptr,
    int n_nodes, int NB, int C, int n_edges)
{
    __shared__ int hist[TILE_NODES];
    __shared__ int scan[TILE_NODES];
    __shared__ int cur[TILE_NODES];
    const int t = blockIdx.x;
    const int beg = off[t * C];
    const int end = (t + 1 < NB) ? off[(t + 1) * C] : n_edges;
    const int node_base = t * TILE_NODES;
    const int n_valid = min(TILE_NODES, n_nodes - node_base);

    if (threadIdx.x < TILE_NODES) hist[threadIdx.x] = 0;
    __syncthreads();
    for (int e = beg + threadIdx.x; e < end; e += 1024)
        atomicAdd(&hist[ebuf[e] >> 17], 1);
    __syncthreads();
    if (threadIdx.x < TILE_NODES) scan[threadIdx.x] = hist[threadIdx.x];
    __syncthreads();
    for (int o = 1; o < TILE_NODES; o <<= 1) {
        int v = 0;
        if (threadIdx.x < TILE_NODES && threadIdx.x >= o) v = scan[threadIdx.x - o];
        __syncthreads();
        if (threadIdx.x < TILE_NODES) scan[threadIdx.x] += v;
        __syncthreads();
    }
    if (threadIdx.x < TILE_NODES) {
        const int ex = scan[threadIdx.x] - hist[threadIdx.x];   // exclusive
        cur[threadIdx.x] = ex;
        if (threadIdx.x < n_valid) ptr[node_base + threadIdx.x] = beg + ex;
    }
    if (t == NB - 1 && threadIdx.x == 0) ptr[n_nodes] = n_edges;
    __syncthreads();
    for (int e = beg + threadIdx.x; e < end; e += 1024) {
        const unsigned int v = ebuf[e];
        const int dl = (int)(v >> 17);
        const int pos = beg + atomicAdd(&cur[dl], 1);
        eidx[pos] = (int)(v & 0x1FFFFu);
    }
}

// ---------------- Layer 0: A(fp8) = x@Wn0 ; B = x@Ws0 + bn0 ----------------
// straight weight layout: sWn[k*32+j] b32 reads (consecutive j -> conflict-free);
// x reads float4 (rows are 128-float stride: 2 distinct addrs/wave, 2-way = free)
__global__ __launch_bounds__(256) void k_layer0(
    const float* __restrict__ x, const float* __restrict__ Wn0,
    const float* __restrict__ bn0, const float* __restrict__ Ws0,
    unsigned char* __restrict__ Ab, float* __restrict__ B, int n_nodes)
{
    __shared__ float sWn[128 * 32];
    __shared__ float sWs[128 * 32];
    __shared__ float sx[32 * 128];

    for (int i = threadIdx.x; i < 128 * 32; i += 256) {
        sWn[i] = Wn0[i];
        sWs[i] = Ws0[i];
    }
    const int tile = blockIdx.x * 32;
    {
        const float4* s4 = (const float4*)(x + (size_t)tile * 128);
        const int lim = (n_nodes - tile) * 32;
#pragma unroll
        for (int m = 0; m < 4; ++m) {
            int i = threadIdx.x + m * 256;
            if (i < lim) ((float4*)sx)[i] = s4[i];
        }
    }
    const int j = threadIdx.x & 31;
    const int r = threadIdx.x >> 5;
    const float bias = bn0[j];
    __syncthreads();

    float accA[4] = {0.f, 0.f, 0.f, 0.f};
    float accB[4] = {bias, bias, bias, bias};
    for (int k = 0; k < 128; k += 4) {
        const float wn0 = sWn[(k + 0) * 32 + j], ws0 = sWs[(k + 0) * 32 + j];
        const float wn1 = sWn[(k + 1) * 32 + j], ws1 = sWs[(k + 1) * 32 + j];
        const float wn2 = sWn[(k + 2) * 32 + j], ws2 = sWs[(k + 2) * 32 + j];
        const float wn3 = sWn[(k + 3) * 32 + j], ws3 = sWs[(k + 3) * 32 + j];
#pragma unroll
        for (int m = 0; m < 4; ++m) {
            const float4 xv = *(const float4*)(sx + (r + 8 * m) * 128 + k);
            accA[m] += xv.x * wn0 + xv.y * wn1 + xv.z * wn2 + xv.w * wn3;
            accB[m] += xv.x * ws0 + xv.y * ws1 + xv.z * ws2 + xv.w * ws3;
        }
    }
#pragma unroll
    for (int m = 0; m < 4; ++m) {
        const int node = tile + r + 8 * m;
        if (node < n_nodes) {
            Ab[(size_t)node * 32 + j] = f2fp8(accA[m]);
            B[(size_t)node * 32 + j] = accB[m];
        }
    }
}

// ------------- Layers 1..3 (in-place on B): A(fp8) = relu(B)@Wn ; B = relu(B)@Ws + bn -------------
__global__ __launch_bounds__(256) void k_layer(
    float* HB,                       // read pre-act, overwritten with new B
    const float* __restrict__ Wn, const float* __restrict__ bnv,
    const float* __restrict__ Ws, unsigned char* __restrict__ Ab, int n_nodes)
{
    __shared__ float sWn[32 * 32];
    __shared__ float sWs[32 * 32];
    __shared__ float sh[64 * 32];

    for (int i = threadIdx.x; i < 1024; i += 256) {
        sWn[i] = Wn[i];
        sWs[i] = Ws[i];
    }
    const int tile = blockIdx.x * 64;
    {
        const float4* s4 = (const float4*)(HB + (size_t)tile * 32);
        const int lim = (n_nodes - tile) * 8;
#pragma unroll
        for (int m = 0; m < 2; ++m) {
            int i = threadIdx.x + m * 256;
            if (i < lim) {
                float4 v = s4[i];
                v.x = fmaxf(v.x, 0.f); v.y = fmaxf(v.y, 0.f);
                v.z = fmaxf(v.z, 0.f); v.w = fmaxf(v.w, 0.f);
                ((float4*)sh)[i] = v;
            }
        }
    }
    const int j = threadIdx.x & 31;
    const int r = threadIdx.x >> 5;
    const float bias = bnv[j];
    __syncthreads();

    float accA[8] = {0.f};
    float accB[8];
#pragma unroll
    for (int m = 0; m < 8; ++m) accB[m] = bias;
    for (int k = 0; k < 32; k += 4) {
        const float wn0 = sWn[(k + 0) * 32 + j], ws0 = sWs[(k + 0) * 32 + j];
        const float wn1 = sWn[(k + 1) * 32 + j], ws1 = sWs[(k + 1) * 32 + j];
        const float wn2 = sWn[(k + 2) * 32 + j], ws2 = sWs[(k + 2) * 32 + j];
        const float wn3 = sWn[(k + 3) * 32 + j], ws3 = sWs[(k + 3) * 32 + j];
#pragma unroll
        for (int m = 0; m < 8; ++m) {
            const float4 hv = *(const float4*)(sh + (r + 8 * m) * 32 + k);
            accA[m] += hv.x * wn0 + hv.y * wn1 + hv.z * wn2 + hv.w * wn3;
            accB[m] += hv.x * ws0 + hv.y * ws1 + hv.z * ws2 + hv.w * ws3;
        }
    }
#pragma unroll
    for (int m = 0; m < 8; ++m) {
        const int node = tile + r + 8 * m;
        if (node < n_nodes) {
            Ab[(size_t)node * 32 + j] = f2fp8(accA[m]);
            HB[(size_t)node * 32 + j] = accB[m];
        }
    }
}

// ------------- Aggregation: B[n] += sum_{e in CSR[n]} A_fp8[eidx[e]] -------------
// 4 lanes per node (uint2 = 8 fp8 each), 8-edge unrolled batches, HW fp8 cvt.
__global__ __launch_bounds__(256) void k_agg2(
    const int* __restrict__ ptr, const int* __restrict__ eidx,
    const unsigned char* __restrict__ Ab, float* __restrict__ B, int n_nodes)
{
    const int g    = blockIdx.x * 64 + (threadIdx.x >> 2);
    const int lane = threadIdx.x & 3;
    if (g >= n_nodes) return;
    const int beg = ptr[g];
    const int end = ptr[g + 1];
    const uint2* __restrict__ A2 = (const uint2*)Ab;   // 8B = 8 fp8
    float4* B4 = (float4*)B;

    float4 a0 = B4[(size_t)g * 8 + lane * 2 + 0];      // cols 8l..8l+3
    float4 a1 = B4[(size_t)g * 8 + lane * 2 + 1];      // cols 8l+4..8l+7
    for (int e = beg; e < end; e += 8) {
        int idx[8];
#pragma unroll
        for (int u = 0; u < 8; ++u)
            idx[u] = (e + u < end) ? eidx[e + u] : -1;
#pragma unroll
        for (int u = 0; u < 8; ++u) {
            if (idx[u] >= 0) {
                const uint2 rw = A2[(size_t)idx[u] * 4 + lane];
                acc8_fp8(rw.x, rw.y, a0, a1);
            }
        }
    }
    B4[(size_t)g * 8 + lane * 2 + 0] = a0;
    B4[(size_t)g * 8 + lane * 2 + 1] = a1;
}

// ---------------- Zero hg ----------------
__global__ __launch_bounds__(256) void k_zero_f(float* __restrict__ p, int n)
{
    int i = blockIdx.x * 256 + threadIdx.x;
    if (i < n) p[i] = 0.f;
}

// ---------------- Node-parallel per-graph sum pool ----------------
__global__ __launch_bounds__(256) void k_pool1(
    const float* __restrict__ H, const int* __restrict__ gids,
    float* __restrict__ hg, int n_nodes)
{
    const int base = blockIdx.x * 128;
    const int lim  = min(base + 128, n_nodes);
    const int j = threadIdx.x & 31;
    const int r = threadIdx.x >> 5;

    int curg = -1;
    float acc = 0.f;
    for (int n = base + r; n < lim; n += 8) {
        const int g = gids[n];
        const float v = fmaxf(H[(size_t)n * 32 + j], 0.f);
        if (g != curg) {
            if (curg >= 0) atomicAdd(&hg[curg * 32 + j], acc);
            curg = g;
            acc = v;
        } else {
            acc += v;
        }
    }
    if (curg >= 0) atomicAdd(&hg[curg * 32 + j], acc);
}

// ---------------- FC head + softmax ----------------
__global__ __launch_bounds__(64) void k_head(
    const float* __restrict__ hg,
    const float* __restrict__ Wfc1, const float* __restrict__ bfc1,
    const float* __restrict__ Wout, const float* __restrict__ bout,
    float* __restrict__ out, int n_graphs)
{
    const int g = blockIdx.x * blockDim.x + threadIdx.x;
    if (g >= n_graphs) return;
    float h[32];
#pragma unroll
    for (int k = 0; k < 32; ++k) h[k] = hg[g * 32 + k];
    float z[8];
#pragma unroll
    for (int m = 0; m < 8; ++m) {
        float a = bfc1[m];
#pragma unroll
        for (int k = 0; k < 32; ++k) a += h[k] * Wfc1[k * 8 + m];
        z[m] = fmaxf(a, 0.f);
    }
    float o[4];
#pragma unroll
    for (int q = 0; q < 4; ++q) {
        float a = bout[q];
#pragma unroll
        for (int m = 0; m < 8; ++m) a += z[m] * Wout[m * 4 + q];
        o[q] = fmaxf(a, 0.f);
    }
    const float mx = fmaxf(fmaxf(o[0], o[1]), fmaxf(o[2], o[3]));
    const float e0 = expf(o[0] - mx), e1 = expf(o[1] - mx);
    const float e2 = expf(o[2] - mx), e3 = expf(o[3] - mx);
    const float inv = 1.f / (e0 + e1 + e2 + e3);
    out[g * 4 + 0] = e0 * inv;
    out[g * 4 + 1] = e1 * inv;
    out[g * 4 + 2] = e2 * inv;
    out[g * 4 + 3] = e3 * inv;
}

extern "C" void kernel_launch(void* const* d_in, const int* in_sizes, int n_in,
                              void* d_out, int out_size, void* d_ws, size_t ws_size,
                              hipStream_t stream)
{
    const float* x    = (const float*)d_in[0];
    const float* Wn0  = (const float*)d_in[1];
    const float* bn0  = (const float*)d_in[2];
    const float* Ws0  = (const float*)d_in[3];
    const float* Wn   = (const float*)d_in[4];   // [3,32,32]
    const float* bn   = (const float*)d_in[5];   // [3,32]
    const float* Ws   = (const float*)d_in[6];   // [3,32,32]
    const float* Wfc1 = (const float*)d_in[7];
    const float* bfc1 = (const float*)d_in[8];
    const float* Wout = (const float*)d_in[9];
    const float* bout = (const float*)d_in[10];
    const int*   src  = (const int*)d_in[11];
    const int*   dst  = (const int*)d_in[12];
    const int*   gids = (const int*)d_in[13];

    const int n_nodes  = in_sizes[0] / 128;
    const int n_edges  = in_sizes[11];
    const int n_graphs = out_size / 4;
    const size_t N32 = (size_t)n_nodes * 32;

    const int NB = (n_nodes + TILE_NODES - 1) / TILE_NODES;
    const int C  = (n_edges + CE - 1) / CE;
    const int n_off = NB * C;

    unsigned char* Ab = (unsigned char*)d_ws;            // [N,32] fp8 (N32 bytes)
    float* B   = (float*)(Ab + N32);                     // [N,32] fp32 (in-place)
    float* hg  = B + N32;                                // [G,32]
    int* histT = (int*)(hg + (size_t)n_graphs * 32);     // [NB*C]
    int* off   = histT + n_off;                          // [NB*C + 1]
    int* part  = off + n_off + 1;                        // [<=256]
    int* ptr   = part + 256;                             // [N+1]
    unsigned int* ebuf = (unsigned int*)(ptr + n_nodes + 1);  // [E]
    int* eidx  = (int*)(ebuf + n_edges);                 // [E]

    const int nparts = (n_off + SCAN_CHUNK - 1) / SCAN_CHUNK;

    // ---- edge sort (once per call; reused by all 4 layers) ----
    k_hist2<<<C, 1024, 0, stream>>>(dst, histT, n_edges, NB, C);
    k_chunk_sum<<<nparts, 256, 0, stream>>>(histT, part, n_off);
    k_scan_part<<<1, 64, 0, stream>>>(part, nparts);
    k_write_off<<<nparts, 256, 0, stream>>>(histT, part, off, n_off, n_edges);
    k_binfill<<<C, 1024, 0, stream>>>(src, dst, off, ebuf, n_edges, NB, C);
    k_tile_sort<<<NB, 1024, 0, stream>>>(off, ebuf, eidx, ptr, n_nodes, NB, C, n_edges);

    const int mblocks0 = (n_nodes + 31) / 32;
    const int mblocks  = (n_nodes + 63) / 64;
    const int ablocks  = (n_nodes + 63) / 64;

    // ---- Layer 0 ----
    k_layer0<<<mblocks0, 256, 0, stream>>>(x, Wn0, bn0, Ws0, Ab, B, n_nodes);
    k_agg2<<<ablocks, 256, 0, stream>>>(ptr, eidx, Ab, B, n_nodes);

    // ---- Layers 1..3 (in-place on B) ----
    for (int l = 0; l < 3; ++l) {
        k_layer<<<mblocks, 256, 0, stream>>>(B, Wn + l * 1024, bn + l * 32,
                                             Ws + l * 1024, Ab, n_nodes);
        k_agg2<<<ablocks, 256, 0, stream>>>(ptr, eidx, Ab, B, n_nodes);
    }

    // ---- Pool + head ----
    k_zero_f<<<(n_graphs * 32 + 255) / 256, 256, 0, stream>>>(hg, n_graphs * 32);
    k_pool1<<<(n_nodes + 127) / 128, 256, 0, stream>>>(B, gids, hg, n_nodes);
    k_head<<<(n_graphs + 63) / 64, 64, 0, stream>>>(hg, Wfc1, bfc1, Wout, bout,
                                                    (float*)d_out, n_graphs);
}

// Round 10
// 438.435 us; speedup vs baseline: 1.2364x; 1.1173x over previous
//
#include <hip/hip_runtime.h>
#include <hip/hip_bf16.h>
#include <math.h>

// GCN forward: 4 GraphConv layers + sum-pool + FC head + softmax.
// N_NODES=100000, N_EDGES=3200000, N_GRAPHS=64, IN=128, DIM=32.
//
// Round-10 (round-9 + compile fix: cvt_pkrtz returns __fp16 vec, not _Float16):
//  - Transform kernels use packed f16 dot2 (v_dot2_f32_f16): halves VALU
//    instr count and LDS traffic vs fp32 FMA. fp32 accumulation.
//  - A stays fp8 e4m3fn (3.2 MB, per-XCD-L2-resident).
//  - agg2: 16-edge unrolled batches for deeper memory-level parallelism.

#define TILE_NODES 256
#define CE 12800                 // edges per sort chunk
#define SCAN_CHUNK 2048
#define MAX_NB 1024

// ---- fp8 e4m3fn software encode (RTN-even) ----
__device__ inline unsigned char f2fp8(float f) {
    unsigned u = __float_as_uint(f);
    unsigned s = (u >> 24) & 0x80u;
    float a = fminf(fabsf(f), 448.f);
    unsigned v = __float_as_uint(a * 0x1p-120f);   // e4m3 window -> f32 exp field
    v = v + 0xFFFFFu + ((v >> 20) & 1u);           // RTN-even to 3 mantissa bits
    return (unsigned char)(s | ((v >> 20) & 0x7Fu));
}
__device__ inline float fp8_dec(unsigned x) {      // one byte, software fallback
    unsigned v = ((x & 0x80u) << 24) | ((x & 0x7Fu) << 20);
    return __uint_as_float(v) * 0x1p120f;
}

typedef float v2f __attribute__((ext_vector_type(2)));
typedef _Float16 h2 __attribute__((ext_vector_type(2)));
typedef __fp16 p2 __attribute__((ext_vector_type(2)));
union U32H2 { unsigned u; h2 h; p2 p; };

__device__ inline unsigned packh2(float a, float b) {
#if __has_builtin(__builtin_amdgcn_cvt_pkrtz)
    U32H2 t; t.p = __builtin_amdgcn_cvt_pkrtz(a, b); return t.u;
#else
    U32H2 t; t.h.x = (_Float16)a; t.h.y = (_Float16)b; return t.u;
#endif
}
__device__ inline float dot2(unsigned a, unsigned b, float c) {
    U32H2 ua, ub; ua.u = a; ub.u = b;
#if __has_builtin(__builtin_amdgcn_fdot2)
    return __builtin_amdgcn_fdot2(ua.h, ub.h, c, false);
#else
    return c + (float)ua.h.x * (float)ub.h.x + (float)ua.h.y * (float)ub.h.y;
#endif
}

// accumulate 8 fp8 (two dwords) into two float4 accumulators
__device__ inline void acc8_fp8(unsigned w0, unsigned w1, float4& a0, float4& a1) {
#if __has_builtin(__builtin_amdgcn_cvt_pk_f32_fp8)
    v2f p0 = __builtin_amdgcn_cvt_pk_f32_fp8(w0, 0);
    v2f p1 = __builtin_amdgcn_cvt_pk_f32_fp8(w0, 1);
    v2f p2v = __builtin_amdgcn_cvt_pk_f32_fp8(w1, 0);
    v2f p3 = __builtin_amdgcn_cvt_pk_f32_fp8(w1, 1);
    a0.x += p0.x; a0.y += p0.y; a0.z += p1.x; a0.w += p1.y;
    a1.x += p2v.x; a1.y += p2v.y; a1.z += p3.x; a1.w += p3.y;
#else
    a0.x += fp8_dec(w0 & 0xFFu);         a0.y += fp8_dec((w0 >> 8) & 0xFFu);
    a0.z += fp8_dec((w0 >> 16) & 0xFFu); a0.w += fp8_dec(w0 >> 24);
    a1.x += fp8_dec(w1 & 0xFFu);         a1.y += fp8_dec((w1 >> 8) & 0xFFu);
    a1.z += fp8_dec((w1 >> 16) & 0xFFu); a1.w += fp8_dec(w1 >> 24);
#endif
}

// ---------------- Pass 1: per-chunk histogram over dst tiles ----------------
__global__ __launch_bounds__(1024) void k_hist2(
    const int* __restrict__ dst, int* __restrict__ histT,
    int n_edges, int NB, int C)
{
    __shared__ int hist[MAX_NB];
    const int c = blockIdx.x;
    for (int b = threadIdx.x; b < NB; b += 1024) hist[b] = 0;
    __syncthreads();
    const int beg = c * CE;
    const int end = min(beg + CE, n_edges);
    for (int e = beg + threadIdx.x; e < end; e += 1024)
        atomicAdd(&hist[dst[e] >> 8], 1);
    __syncthreads();
    for (int b = threadIdx.x; b < NB; b += 1024)
        histT[b * C + c] = hist[b];
}

// ---------------- Pass 2: hierarchical exclusive scan of histT ----------------
__global__ __launch_bounds__(256) void k_chunk_sum(
    const int* __restrict__ v, int* __restrict__ part, int n)
{
    __shared__ int red[256];
    const int base = blockIdx.x * SCAN_CHUNK;
    int s = 0;
    for (int i = threadIdx.x; i < SCAN_CHUNK; i += 256) {
        int idx = base + i;
        if (idx < n) s += v[idx];
    }
    red[threadIdx.x] = s;
    __syncthreads();
    for (int off = 128; off > 0; off >>= 1) {
        if (threadIdx.x < off) red[threadIdx.x] += red[threadIdx.x + off];
        __syncthreads();
    }
    if (threadIdx.x == 0) part[blockIdx.x] = red[0];
}

__global__ void k_scan_part(int* __restrict__ part, int nparts)
{
    if (threadIdx.x == 0 && blockIdx.x == 0) {
        int run = 0;
        for (int i = 0; i < nparts; ++i) { int v = part[i]; part[i] = run; run += v; }
    }
}

__global__ __launch_bounds__(256) void k_write_off(
    const int* __restrict__ v, const int* __restrict__ part,
    int* __restrict__ off, int n, int total)
{
    __shared__ int lds[256];
    const int tid   = threadIdx.x;
    const int base  = blockIdx.x * SCAN_CHUNK;
    const int tbase = base + tid * 8;
    int c[8];
    int tot = 0;
#pragma unroll
    for (int m = 0; m < 8; ++m) {
        int idx = tbase + m;
        c[m] = (idx < n) ? v[idx] : 0;
        tot += c[m];
    }
    lds[tid] = tot;
    __syncthreads();
    for (int o = 1; o < 256; o <<= 1) {
        int val = (tid >= o) ? lds[tid - o] : 0;
        __syncthreads();
        lds[tid] += val;
        __syncthreads();
    }
    int run = part[blockIdx.x] + lds[tid] - tot;
#pragma unroll
    for (int m = 0; m < 8; ++m) {
        int idx = tbase + m;
        if (idx < n) off[idx] = run;
        run += c[m];
    }
    if (blockIdx.x == 0 && tid == 0) off[n] = total;
}

// ---------------- Pass 3: bin packed edges into tile regions ----------------
__global__ __launch_bounds__(1024) void k_binfill(
    const int* __restrict__ src, const int* __restrict__ dst,
    const int* __restrict__ off, unsigned int* __restrict__ ebuf,
    int n_edges, int NB, int C)
{
    __shared__ int lcur[MAX_NB];
    const int c = blockIdx.x;
    for (int b = threadIdx.x; b < NB; b += 1024)
        lcur[b] = off[b * C + c];
    __syncthreads();
    const int beg = c * CE;
    const int end = min(beg + CE, n_edges);
    for (int e = beg + threadIdx.x; e < end; e += 1024) {
        const int d = dst[e];
        const int b = d >> 8;
        const unsigned int dl = (unsigned int)(d & 255);
        const int pos = atomicAdd(&lcur[b], 1);
        ebuf[pos] = (dl << 17) | (unsigned int)src[e];
    }
}

// ---------------- Pass 4: per-tile counting sort -> eidx + ptr ----------------
__global__ __launch_bounds__(1024) void k_tile_sort(
    const int* __restrict__ off, const unsigned int* __restrict__ ebuf,
    int* __restrict__ eidx, int* __restrict__ ptr,
    int n_nodes, int NB, int C, int n_edges)
{
    __shared__ int hist[TILE_NODES];
    __shared__ int scan[TILE_NODES];
    __shared__ int cur[TILE_NODES];
    const int t = blockIdx.x;
    const int beg = off[t * C];
    const int end = (t + 1 < NB) ? off[(t + 1) * C] : n_edges;
    const int node_base = t * TILE_NODES;
    const int n_valid = min(TILE_NODES, n_nodes - node_base);

    if (threadIdx.x < TILE_NODES) hist[threadIdx.x] = 0;
    __syncthreads();
    for (int e = beg + threadIdx.x; e < end; e += 1024)
        atomicAdd(&hist[ebuf[e] >> 17], 1);
    __syncthreads();
    if (threadIdx.x < TILE_NODES) scan[threadIdx.x] = hist[threadIdx.x];
    __syncthreads();
    for (int o = 1; o < TILE_NODES; o <<= 1) {
        int v = 0;
        if (threadIdx.x < TILE_NODES && threadIdx.x >= o) v = scan[threadIdx.x - o];
        __syncthreads();
        if (threadIdx.x < TILE_NODES) scan[threadIdx.x] += v;
        __syncthreads();
    }
    if (threadIdx.x < TILE_NODES) {
        const int ex = scan[threadIdx.x] - hist[threadIdx.x];   // exclusive
        cur[threadIdx.x] = ex;
        if (threadIdx.x < n_valid) ptr[node_base + threadIdx.x] = beg + ex;
    }
    if (t == NB - 1 && threadIdx.x == 0) ptr[n_nodes] = n_edges;
    __syncthreads();
    for (int e = beg + threadIdx.x; e < end; e += 1024) {
        const unsigned int v = ebuf[e];
        const int dl = (int)(v >> 17);
        const int pos = beg + atomicAdd(&cur[dl], 1);
        eidx[pos] = (int)(v & 0x1FFFFu);
    }
}

// ---------------- Layer 0: A(fp8) = x@Wn0 ; B = x@Ws0 + bn0 ----------------
// f16 dot2 path. LDS: weights as half2 k-pairs [k2][j] (b32 reads, conflict-
// free broadcast), x rows as half2 [node][k2] (uint4 = 8 k per read).
__global__ __launch_bounds__(256) void k_layer0(
    const float* __restrict__ x, const float* __restrict__ Wn0,
    const float* __restrict__ bn0, const float* __restrict__ Ws0,
    unsigned char* __restrict__ Ab, float* __restrict__ B, int n_nodes)
{
    __shared__ unsigned sWn[64 * 32];   // [k2][j]
    __shared__ unsigned sWs[64 * 32];
    __shared__ unsigned sx[32 * 64];    // [row][k2]

    for (int i = threadIdx.x; i < 64 * 32; i += 256) {
        const int k2 = i >> 5, jj = i & 31;
        sWn[i] = packh2(Wn0[(2 * k2) * 32 + jj], Wn0[(2 * k2 + 1) * 32 + jj]);
        sWs[i] = packh2(Ws0[(2 * k2) * 32 + jj], Ws0[(2 * k2 + 1) * 32 + jj]);
    }
    const int tile = blockIdx.x * 32;
    {
        const float4* s4 = (const float4*)(x + (size_t)tile * 128);
        const int lim = (n_nodes - tile) * 32;   // float4 count
#pragma unroll
        for (int m = 0; m < 4; ++m) {
            int i = threadIdx.x + m * 256;
            if (i < lim) {
                float4 v = s4[i];
                const int row = i >> 5, q = i & 31;
                sx[row * 64 + 2 * q]     = packh2(v.x, v.y);
                sx[row * 64 + 2 * q + 1] = packh2(v.z, v.w);
            }
        }
    }
    const int j = threadIdx.x & 31;
    const int r = threadIdx.x >> 5;
    const float bias = bn0[j];
    __syncthreads();

    float accA[4] = {0.f, 0.f, 0.f, 0.f};
    float accB[4] = {bias, bias, bias, bias};
    for (int k2 = 0; k2 < 64; k2 += 4) {
        const unsigned wn0 = sWn[(k2 + 0) * 32 + j], ws0 = sWs[(k2 + 0) * 32 + j];
        const unsigned wn1 = sWn[(k2 + 1) * 32 + j], ws1 = sWs[(k2 + 1) * 32 + j];
        const unsigned wn2 = sWn[(k2 + 2) * 32 + j], ws2 = sWs[(k2 + 2) * 32 + j];
        const unsigned wn3 = sWn[(k2 + 3) * 32 + j], ws3 = sWs[(k2 + 3) * 32 + j];
#pragma unroll
        for (int m = 0; m < 4; ++m) {
            const uint4 xv = *(const uint4*)(sx + (r + 8 * m) * 64 + k2);
            accA[m] = dot2(xv.x, wn0, accA[m]);
            accA[m] = dot2(xv.y, wn1, accA[m]);
            accA[m] = dot2(xv.z, wn2, accA[m]);
            accA[m] = dot2(xv.w, wn3, accA[m]);
            accB[m] = dot2(xv.x, ws0, accB[m]);
            accB[m] = dot2(xv.y, ws1, accB[m]);
            accB[m] = dot2(xv.z, ws2, accB[m]);
            accB[m] = dot2(xv.w, ws3, accB[m]);
        }
    }
#pragma unroll
    for (int m = 0; m < 4; ++m) {
        const int node = tile + r + 8 * m;
        if (node < n_nodes) {
            Ab[(size_t)node * 32 + j] = f2fp8(accA[m]);
            B[(size_t)node * 32 + j] = accB[m];
        }
    }
}

// ------------- Layers 1..3 (in-place on B): A(fp8) = relu(B)@Wn ; B = relu(B)@Ws + bn -------------
__global__ __launch_bounds__(256) void k_layer(
    float* HB,                       // read pre-act, overwritten with new B
    const float* __restrict__ Wn, const float* __restrict__ bnv,
    const float* __restrict__ Ws, unsigned char* __restrict__ Ab, int n_nodes)
{
    __shared__ unsigned sWn[16 * 32];   // [k2][j]
    __shared__ unsigned sWs[16 * 32];
    __shared__ unsigned sh[64 * 16];    // [row][k2]

    for (int i = threadIdx.x; i < 16 * 32; i += 256) {
        const int k2 = i >> 5, jj = i & 31;
        sWn[i] = packh2(Wn[(2 * k2) * 32 + jj], Wn[(2 * k2 + 1) * 32 + jj]);
        sWs[i] = packh2(Ws[(2 * k2) * 32 + jj], Ws[(2 * k2 + 1) * 32 + jj]);
    }
    const int tile = blockIdx.x * 64;
    {
        const float4* s4 = (const float4*)(HB + (size_t)tile * 32);
        const int lim = (n_nodes - tile) * 8;   // float4 count
#pragma unroll
        for (int m = 0; m < 2; ++m) {
            int i = threadIdx.x + m * 256;
            if (i < lim) {
                float4 v = s4[i];
                v.x = fmaxf(v.x, 0.f); v.y = fmaxf(v.y, 0.f);
                v.z = fmaxf(v.z, 0.f); v.w = fmaxf(v.w, 0.f);
                const int row = i >> 3, q = i & 7;
                sh[row * 16 + 2 * q]     = packh2(v.x, v.y);
                sh[row * 16 + 2 * q + 1] = packh2(v.z, v.w);
            }
        }
    }
    const int j = threadIdx.x & 31;
    const int r = threadIdx.x >> 5;
    const float bias = bnv[j];
    __syncthreads();

    float accA[8] = {0.f};
    float accB[8];
#pragma unroll
    for (int m = 0; m < 8; ++m) accB[m] = bias;
#pragma unroll
    for (int k2 = 0; k2 < 16; k2 += 4) {
        const unsigned wn0 = sWn[(k2 + 0) * 32 + j], ws0 = sWs[(k2 + 0) * 32 + j];
        const unsigned wn1 = sWn[(k2 + 1) * 32 + j], ws1 = sWs[(k2 + 1) * 32 + j];
        const unsigned wn2 = sWn[(k2 + 2) * 32 + j], ws2 = sWs[(k2 + 2) * 32 + j];
        const unsigned wn3 = sWn[(k2 + 3) * 32 + j], ws3 = sWs[(k2 + 3) * 32 + j];
#pragma unroll
        for (int m = 0; m < 8; ++m) {
            const uint4 hv = *(const uint4*)(sh + (r + 8 * m) * 16 + k2);
            accA[m] = dot2(hv.x, wn0, accA[m]);
            accA[m] = dot2(hv.y, wn1, accA[m]);
            accA[m] = dot2(hv.z, wn2, accA[m]);
            accA[m] = dot2(hv.w, wn3, accA[m]);
            accB[m] = dot2(hv.x, ws0, accB[m]);
            accB[m] = dot2(hv.y, ws1, accB[m]);
            accB[m] = dot2(hv.z, ws2, accB[m]);
            accB[m] = dot2(hv.w, ws3, accB[m]);
        }
    }
#pragma unroll
    for (int m = 0; m < 8; ++m) {
        const int node = tile + r + 8 * m;
        if (node < n_nodes) {
            Ab[(size_t)node * 32 + j] = f2fp8(accA[m]);
            HB[(size_t)node * 32 + j] = accB[m];
        }
    }
}

// ------------- Aggregation: B[n] += sum_{e in CSR[n]} A_fp8[eidx[e]] -------------
// 4 lanes per node (uint2 = 8 fp8 each), 16-edge unrolled batches, HW fp8 cvt.
__global__ __launch_bounds__(256) void k_agg2(
    const int* __restrict__ ptr, const int* __restrict__ eidx,
    const unsigned char* __restrict__ Ab, float* __restrict__ B, int n_nodes)
{
    const int g    = blockIdx.x * 64 + (threadIdx.x >> 2);
    const int lane = threadIdx.x & 3;
    if (g >= n_nodes) return;
    const int beg = ptr[g];
    const int end = ptr[g + 1];
    const uint2* __restrict__ A2 = (const uint2*)Ab;   // 8B = 8 fp8
    float4* B4 = (float4*)B;

    float4 a0 = B4[(size_t)g * 8 + lane * 2 + 0];      // cols 8l..8l+3
    float4 a1 = B4[(size_t)g * 8 + lane * 2 + 1];      // cols 8l+4..8l+7
    for (int e = beg; e < end; e += 16) {
        int idx[16];
#pragma unroll
        for (int u = 0; u < 16; ++u)
            idx[u] = (e + u < end) ? eidx[e + u] : -1;
#pragma unroll
        for (int u = 0; u < 16; ++u) {
            if (idx[u] >= 0) {
                const uint2 rw = A2[(size_t)idx[u] * 4 + lane];
                acc8_fp8(rw.x, rw.y, a0, a1);
            }
        }
    }
    B4[(size_t)g * 8 + lane * 2 + 0] = a0;
    B4[(size_t)g * 8 + lane * 2 + 1] = a1;
}

// ---------------- Zero hg ----------------
__global__ __launch_bounds__(256) void k_zero_f(float* __restrict__ p, int n)
{
    int i = blockIdx.x * 256 + threadIdx.x;
    if (i < n) p[i] = 0.f;
}

// ---------------- Node-parallel per-graph sum pool ----------------
__global__ __launch_bounds__(256) void k_pool1(
    const float* __restrict__ H, const int* __restrict__ gids,
    float* __restrict__ hg, int n_nodes)
{
    const int base = blockIdx.x * 128;
    const int lim  = min(base + 128, n_nodes);
    const int j = threadIdx.x & 31;
    const int r = threadIdx.x >> 5;

    int curg = -1;
    float acc = 0.f;
    for (int n = base + r; n < lim; n += 8) {
        const int g = gids[n];
        const float v = fmaxf(H[(size_t)n * 32 + j], 0.f);
        if (g != curg) {
            if (curg >= 0) atomicAdd(&hg[curg * 32 + j], acc);
            curg = g;
            acc = v;
        } else {
            acc += v;
        }
    }
    if (curg >= 0) atomicAdd(&hg[curg * 32 + j], acc);
}

// ---------------- FC head + softmax ----------------
__global__ __launch_bounds__(64) void k_head(
    const float* __restrict__ hg,
    const float* __restrict__ Wfc1, const float* __restrict__ bfc1,
    const float* __restrict__ Wout, const float* __restrict__ bout,
    float* __restrict__ out, int n_graphs)
{
    const int g = blockIdx.x * blockDim.x + threadIdx.x;
    if (g >= n_graphs) return;
    float h[32];
#pragma unroll
    for (int k = 0; k < 32; ++k) h[k] = hg[g * 32 + k];
    float z[8];
#pragma unroll
    for (int m = 0; m < 8; ++m) {
        float a = bfc1[m];
#pragma unroll
        for (int k = 0; k < 32; ++k) a += h[k] * Wfc1[k * 8 + m];
        z[m] = fmaxf(a, 0.f);
    }
    float o[4];
#pragma unroll
    for (int q = 0; q < 4; ++q) {
        float a = bout[q];
#pragma unroll
        for (int m = 0; m < 8; ++m) a += z[m] * Wout[m * 4 + q];
        o[q] = fmaxf(a, 0.f);
    }
    const float mx = fmaxf(fmaxf(o[0], o[1]), fmaxf(o[2], o[3]));
    const float e0 = expf(o[0] - mx), e1 = expf(o[1] - mx);
    const float e2 = expf(o[2] - mx), e3 = expf(o[3] - mx);
    const float inv = 1.f / (e0 + e1 + e2 + e3);
    out[g * 4 + 0] = e0 * inv;
    out[g * 4 + 1] = e1 * inv;
    out[g * 4 + 2] = e2 * inv;
    out[g * 4 + 3] = e3 * inv;
}

extern "C" void kernel_launch(void* const* d_in, const int* in_sizes, int n_in,
                              void* d_out, int out_size, void* d_ws, size_t ws_size,
                              hipStream_t stream)
{
    const float* x    = (const float*)d_in[0];
    const float* Wn0  = (const float*)d_in[1];
    const float* bn0  = (const float*)d_in[2];
    const float* Ws0  = (const float*)d_in[3];
    const float* Wn   = (const float*)d_in[4];   // [3,32,32]
    const float* bn   = (const float*)d_in[5];   // [3,32]
    const float* Ws   = (const float*)d_in[6];   // [3,32,32]
    const float* Wfc1 = (const float*)d_in[7];
    const float* bfc1 = (const float*)d_in[8];
    const float* Wout = (const float*)d_in[9];
    const float* bout = (const float*)d_in[10];
    const int*   src  = (const int*)d_in[11];
    const int*   dst  = (const int*)d_in[12];
    const int*   gids = (const int*)d_in[13];

    const int n_nodes  = in_sizes[0] / 128;
    const int n_edges  = in_sizes[11];
    const int n_graphs = out_size / 4;
    const size_t N32 = (size_t)n_nodes * 32;

    const int NB = (n_nodes + TILE_NODES - 1) / TILE_NODES;
    const int C  = (n_edges + CE - 1) / CE;
    const int n_off = NB * C;

    unsigned char* Ab = (unsigned char*)d_ws;            // [N,32] fp8 (N32 bytes)
    float* B   = (float*)(Ab + N32);                     // [N,32] fp32 (in-place)
    float* hg  = B + N32;                                // [G,32]
    int* histT = (int*)(hg + (size_t)n_graphs * 32);     // [NB*C]
    int* off   = histT + n_off;                          // [NB*C + 1]
    int* part  = off + n_off + 1;                        // [<=256]
    int* ptr   = part + 256;                             // [N+1]
    unsigned int* ebuf = (unsigned int*)(ptr + n_nodes + 1);  // [E]
    int* eidx  = (int*)(ebuf + n_edges);                 // [E]

    const int nparts = (n_off + SCAN_CHUNK - 1) / SCAN_CHUNK;

    // ---- edge sort (once per call; reused by all 4 layers) ----
    k_hist2<<<C, 1024, 0, stream>>>(dst, histT, n_edges, NB, C);
    k_chunk_sum<<<nparts, 256, 0, stream>>>(histT, part, n_off);
    k_scan_part<<<1, 64, 0, stream>>>(part, nparts);
    k_write_off<<<nparts, 256, 0, stream>>>(histT, part, off, n_off, n_edges);
    k_binfill<<<C, 1024, 0, stream>>>(src, dst, off, ebuf, n_edges, NB, C);
    k_tile_sort<<<NB, 1024, 0, stream>>>(off, ebuf, eidx, ptr, n_nodes, NB, C, n_edges);

    const int mblocks0 = (n_nodes + 31) / 32;
    const int mblocks  = (n_nodes + 63) / 64;
    const int ablocks  = (n_nodes + 63) / 64;

    // ---- Layer 0 ----
    k_layer0<<<mblocks0, 256, 0, stream>>>(x, Wn0, bn0, Ws0, Ab, B, n_nodes);
    k_agg2<<<ablocks, 256, 0, stream>>>(ptr, eidx, Ab, B, n_nodes);

    // ---- Layers 1..3 (in-place on B) ----
    for (int l = 0; l < 3; ++l) {
        k_layer<<<mblocks, 256, 0, stream>>>(B, Wn + l * 1024, bn + l * 32,
                                             Ws + l * 1024, Ab, n_nodes);
        k_agg2<<<ablocks, 256, 0, stream>>>(ptr, eidx, Ab, B, n_nodes);
    }

    // ---- Pool + head ----
    k_zero_f<<<(n_graphs * 32 + 255) / 256, 256, 0, stream>>>(hg, n_graphs * 32);
    k_pool1<<<(n_nodes + 127) / 128, 256, 0, stream>>>(B, gids, hg, n_nodes);
    k_head<<<(n_graphs + 63) / 64, 64, 0, stream>>>(hg, Wfc1, bfc1, Wout, bout,
                                                    (float*)d_out, n_graphs);
}

// Round 11
// 394.934 us; speedup vs baseline: 1.3726x; 1.1101x over previous
//
#include <hip/hip_runtime.h>
#include <hip/hip_bf16.h>
#include <math.h>

// GCN forward: 4 GraphConv layers + sum-pool + FC head + softmax.
// N_NODES=100000, N_EDGES=3200000, N_GRAPHS=64, IN=128, DIM=32.
//
// Round-11 (= round-10 + register-pressure fix):
//  - k_layer0/k_layer: __launch_bounds__(256,4) + #pragma unroll 2 on the
//    k2 loop. Round-10's implicit full unroll pushed VGPR 68->196 and
//    occupancy 26->10% (the dot2 chains couldn't be latency-hidden).
//  - A stays fp8 e4m3fn (3.2 MB, per-XCD-L2-resident); f16 dot2 transforms;
//    agg2 16-edge batches.

#define TILE_NODES 256
#define CE 12800                 // edges per sort chunk
#define SCAN_CHUNK 2048
#define MAX_NB 1024

// ---- fp8 e4m3fn software encode (RTN-even) ----
__device__ inline unsigned char f2fp8(float f) {
    unsigned u = __float_as_uint(f);
    unsigned s = (u >> 24) & 0x80u;
    float a = fminf(fabsf(f), 448.f);
    unsigned v = __float_as_uint(a * 0x1p-120f);   // e4m3 window -> f32 exp field
    v = v + 0xFFFFFu + ((v >> 20) & 1u);           // RTN-even to 3 mantissa bits
    return (unsigned char)(s | ((v >> 20) & 0x7Fu));
}
__device__ inline float fp8_dec(unsigned x) {      // one byte, software fallback
    unsigned v = ((x & 0x80u) << 24) | ((x & 0x7Fu) << 20);
    return __uint_as_float(v) * 0x1p120f;
}

typedef float v2f __attribute__((ext_vector_type(2)));
typedef _Float16 h2 __attribute__((ext_vector_type(2)));
typedef __fp16 p2 __attribute__((ext_vector_type(2)));
union U32H2 { unsigned u; h2 h; p2 p; };

__device__ inline unsigned packh2(float a, float b) {
#if __has_builtin(__builtin_amdgcn_cvt_pkrtz)
    U32H2 t; t.p = __builtin_amdgcn_cvt_pkrtz(a, b); return t.u;
#else
    U32H2 t; t.h.x = (_Float16)a; t.h.y = (_Float16)b; return t.u;
#endif
}
__device__ inline float dot2(unsigned a, unsigned b, float c) {
    U32H2 ua, ub; ua.u = a; ub.u = b;
#if __has_builtin(__builtin_amdgcn_fdot2)
    return __builtin_amdgcn_fdot2(ua.h, ub.h, c, false);
#else
    return c + (float)ua.h.x * (float)ub.h.x + (float)ua.h.y * (float)ub.h.y;
#endif
}

// accumulate 8 fp8 (two dwords) into two float4 accumulators
__device__ inline void acc8_fp8(unsigned w0, unsigned w1, float4& a0, float4& a1) {
#if __has_builtin(__builtin_amdgcn_cvt_pk_f32_fp8)
    v2f p0 = __builtin_amdgcn_cvt_pk_f32_fp8(w0, 0);
    v2f p1 = __builtin_amdgcn_cvt_pk_f32_fp8(w0, 1);
    v2f p2v = __builtin_amdgcn_cvt_pk_f32_fp8(w1, 0);
    v2f p3 = __builtin_amdgcn_cvt_pk_f32_fp8(w1, 1);
    a0.x += p0.x; a0.y += p0.y; a0.z += p1.x; a0.w += p1.y;
    a1.x += p2v.x; a1.y += p2v.y; a1.z += p3.x; a1.w += p3.y;
#else
    a0.x += fp8_dec(w0 & 0xFFu);         a0.y += fp8_dec((w0 >> 8) & 0xFFu);
    a0.z += fp8_dec((w0 >> 16) & 0xFFu); a0.w += fp8_dec(w0 >> 24);
    a1.x += fp8_dec(w1 & 0xFFu);         a1.y += fp8_dec((w1 >> 8) & 0xFFu);
    a1.z += fp8_dec((w1 >> 16) & 0xFFu); a1.w += fp8_dec(w1 >> 24);
#endif
}

// ---------------- Pass 1: per-chunk histogram over dst tiles ----------------
__global__ __launch_bounds__(1024) void k_hist2(
    const int* __restrict__ dst, int* __restrict__ histT,
    int n_edges, int NB, int C)
{
    __shared__ int hist[MAX_NB];
    const int c = blockIdx.x;
    for (int b = threadIdx.x; b < NB; b += 1024) hist[b] = 0;
    __syncthreads();
    const int beg = c * CE;
    const int end = min(beg + CE, n_edges);
    for (int e = beg + threadIdx.x; e < end; e += 1024)
        atomicAdd(&hist[dst[e] >> 8], 1);
    __syncthreads();
    for (int b = threadIdx.x; b < NB; b += 1024)
        histT[b * C + c] = hist[b];
}

// ---------------- Pass 2: hierarchical exclusive scan of histT ----------------
__global__ __launch_bounds__(256) void k_chunk_sum(
    const int* __restrict__ v, int* __restrict__ part, int n)
{
    __shared__ int red[256];
    const int base = blockIdx.x * SCAN_CHUNK;
    int s = 0;
    for (int i = threadIdx.x; i < SCAN_CHUNK; i += 256) {
        int idx = base + i;
        if (idx < n) s += v[idx];
    }
    red[threadIdx.x] = s;
    __syncthreads();
    for (int off = 128; off > 0; off >>= 1) {
        if (threadIdx.x < off) red[threadIdx.x] += red[threadIdx.x + off];
        __syncthreads();
    }
    if (threadIdx.x == 0) part[blockIdx.x] = red[0];
}

__global__ void k_scan_part(int* __restrict__ part, int nparts)
{
    if (threadIdx.x == 0 && blockIdx.x == 0) {
        int run = 0;
        for (int i = 0; i < nparts; ++i) { int v = part[i]; part[i] = run; run += v; }
    }
}

__global__ __launch_bounds__(256) void k_write_off(
    const int* __restrict__ v, const int* __restrict__ part,
    int* __restrict__ off, int n, int total)
{
    __shared__ int lds[256];
    const int tid   = threadIdx.x;
    const int base  = blockIdx.x * SCAN_CHUNK;
    const int tbase = base + tid * 8;
    int c[8];
    int tot = 0;
#pragma unroll
    for (int m = 0; m < 8; ++m) {
        int idx = tbase + m;
        c[m] = (idx < n) ? v[idx] : 0;
        tot += c[m];
    }
    lds[tid] = tot;
    __syncthreads();
    for (int o = 1; o < 256; o <<= 1) {
        int val = (tid >= o) ? lds[tid - o] : 0;
        __syncthreads();
        lds[tid] += val;
        __syncthreads();
    }
    int run = part[blockIdx.x] + lds[tid] - tot;
#pragma unroll
    for (int m = 0; m < 8; ++m) {
        int idx = tbase + m;
        if (idx < n) off[idx] = run;
        run += c[m];
    }
    if (blockIdx.x == 0 && tid == 0) off[n] = total;
}

// ---------------- Pass 3: bin packed edges into tile regions ----------------
__global__ __launch_bounds__(1024) void k_binfill(
    const int* __restrict__ src, const int* __restrict__ dst,
    const int* __restrict__ off, unsigned int* __restrict__ ebuf,
    int n_edges, int NB, int C)
{
    __shared__ int lcur[MAX_NB];
    const int c = blockIdx.x;
    for (int b = threadIdx.x; b < NB; b += 1024)
        lcur[b] = off[b * C + c];
    __syncthreads();
    const int beg = c * CE;
    const int end = min(beg + CE, n_edges);
    for (int e = beg + threadIdx.x; e < end; e += 1024) {
        const int d = dst[e];
        const int b = d >> 8;
        const unsigned int dl = (unsigned int)(d & 255);
        const int pos = atomicAdd(&lcur[b], 1);
        ebuf[pos] = (dl << 17) | (unsigned int)src[e];
    }
}

// ---------------- Pass 4: per-tile counting sort -> eidx + ptr ----------------
__global__ __launch_bounds__(1024) void k_tile_sort(
    const int* __restrict__ off, const unsigned int* __restrict__ ebuf,
    int* __restrict__ eidx, int* __restrict__ ptr,
    int n_nodes, int NB, int C, int n_edges)
{
    __shared__ int hist[TILE_NODES];
    __shared__ int scan[TILE_NODES];
    __shared__ int cur[TILE_NODES];
    const int t = blockIdx.x;
    const int beg = off[t * C];
    const int end = (t + 1 < NB) ? off[(t + 1) * C] : n_edges;
    const int node_base = t * TILE_NODES;
    const int n_valid = min(TILE_NODES, n_nodes - node_base);

    if (threadIdx.x < TILE_NODES) hist[threadIdx.x] = 0;
    __syncthreads();
    for (int e = beg + threadIdx.x; e < end; e += 1024)
        atomicAdd(&hist[ebuf[e] >> 17], 1);
    __syncthreads();
    if (threadIdx.x < TILE_NODES) scan[threadIdx.x] = hist[threadIdx.x];
    __syncthreads();
    for (int o = 1; o < TILE_NODES; o <<= 1) {
        int v = 0;
        if (threadIdx.x < TILE_NODES && threadIdx.x >= o) v = scan[threadIdx.x - o];
        __syncthreads();
        if (threadIdx.x < TILE_NODES) scan[threadIdx.x] += v;
        __syncthreads();
    }
    if (threadIdx.x < TILE_NODES) {
        const int ex = scan[threadIdx.x] - hist[threadIdx.x];   // exclusive
        cur[threadIdx.x] = ex;
        if (threadIdx.x < n_valid) ptr[node_base + threadIdx.x] = beg + ex;
    }
    if (t == NB - 1 && threadIdx.x == 0) ptr[n_nodes] = n_edges;
    __syncthreads();
    for (int e = beg + threadIdx.x; e < end; e += 1024) {
        const unsigned int v = ebuf[e];
        const int dl = (int)(v >> 17);
        const int pos = beg + atomicAdd(&cur[dl], 1);
        eidx[pos] = (int)(v & 0x1FFFFu);
    }
}

// ---------------- Layer 0: A(fp8) = x@Wn0 ; B = x@Ws0 + bn0 ----------------
// f16 dot2 path; __launch_bounds__(256,4) caps VGPR (round-10 hit 196 VGPR /
// 10% occupancy from implicit full unroll), unroll 2 keeps pressure bounded.
__global__ __launch_bounds__(256, 4) void k_layer0(
    const float* __restrict__ x, const float* __restrict__ Wn0,
    const float* __restrict__ bn0, const float* __restrict__ Ws0,
    unsigned char* __restrict__ Ab, float* __restrict__ B, int n_nodes)
{
    __shared__ unsigned sWn[64 * 32];   // [k2][j]
    __shared__ unsigned sWs[64 * 32];
    __shared__ unsigned sx[32 * 64];    // [row][k2]

    for (int i = threadIdx.x; i < 64 * 32; i += 256) {
        const int k2 = i >> 5, jj = i & 31;
        sWn[i] = packh2(Wn0[(2 * k2) * 32 + jj], Wn0[(2 * k2 + 1) * 32 + jj]);
        sWs[i] = packh2(Ws0[(2 * k2) * 32 + jj], Ws0[(2 * k2 + 1) * 32 + jj]);
    }
    const int tile = blockIdx.x * 32;
    {
        const float4* s4 = (const float4*)(x + (size_t)tile * 128);
        const int lim = (n_nodes - tile) * 32;   // float4 count
#pragma unroll
        for (int m = 0; m < 4; ++m) {
            int i = threadIdx.x + m * 256;
            if (i < lim) {
                float4 v = s4[i];
                const int row = i >> 5, q = i & 31;
                sx[row * 64 + 2 * q]     = packh2(v.x, v.y);
                sx[row * 64 + 2 * q + 1] = packh2(v.z, v.w);
            }
        }
    }
    const int j = threadIdx.x & 31;
    const int r = threadIdx.x >> 5;
    const float bias = bn0[j];
    __syncthreads();

    float accA[4] = {0.f, 0.f, 0.f, 0.f};
    float accB[4] = {bias, bias, bias, bias};
#pragma unroll 2
    for (int k2 = 0; k2 < 64; k2 += 4) {
        const unsigned wn0 = sWn[(k2 + 0) * 32 + j], ws0 = sWs[(k2 + 0) * 32 + j];
        const unsigned wn1 = sWn[(k2 + 1) * 32 + j], ws1 = sWs[(k2 + 1) * 32 + j];
        const unsigned wn2 = sWn[(k2 + 2) * 32 + j], ws2 = sWs[(k2 + 2) * 32 + j];
        const unsigned wn3 = sWn[(k2 + 3) * 32 + j], ws3 = sWs[(k2 + 3) * 32 + j];
#pragma unroll
        for (int m = 0; m < 4; ++m) {
            const uint4 xv = *(const uint4*)(sx + (r + 8 * m) * 64 + k2);
            accA[m] = dot2(xv.x, wn0, accA[m]);
            accA[m] = dot2(xv.y, wn1, accA[m]);
            accA[m] = dot2(xv.z, wn2, accA[m]);
            accA[m] = dot2(xv.w, wn3, accA[m]);
            accB[m] = dot2(xv.x, ws0, accB[m]);
            accB[m] = dot2(xv.y, ws1, accB[m]);
            accB[m] = dot2(xv.z, ws2, accB[m]);
            accB[m] = dot2(xv.w, ws3, accB[m]);
        }
    }
#pragma unroll
    for (int m = 0; m < 4; ++m) {
        const int node = tile + r + 8 * m;
        if (node < n_nodes) {
            Ab[(size_t)node * 32 + j] = f2fp8(accA[m]);
            B[(size_t)node * 32 + j] = accB[m];
        }
    }
}

// ------------- Layers 1..3 (in-place on B): A(fp8) = relu(B)@Wn ; B = relu(B)@Ws + bn -------------
__global__ __launch_bounds__(256, 4) void k_layer(
    float* HB,                       // read pre-act, overwritten with new B
    const float* __restrict__ Wn, const float* __restrict__ bnv,
    const float* __restrict__ Ws, unsigned char* __restrict__ Ab, int n_nodes)
{
    __shared__ unsigned sWn[16 * 32];   // [k2][j]
    __shared__ unsigned sWs[16 * 32];
    __shared__ unsigned sh[64 * 16];    // [row][k2]

    for (int i = threadIdx.x; i < 16 * 32; i += 256) {
        const int k2 = i >> 5, jj = i & 31;
        sWn[i] = packh2(Wn[(2 * k2) * 32 + jj], Wn[(2 * k2 + 1) * 32 + jj]);
        sWs[i] = packh2(Ws[(2 * k2) * 32 + jj], Ws[(2 * k2 + 1) * 32 + jj]);
    }
    const int tile = blockIdx.x * 64;
    {
        const float4* s4 = (const float4*)(HB + (size_t)tile * 32);
        const int lim = (n_nodes - tile) * 8;   // float4 count
#pragma unroll
        for (int m = 0; m < 2; ++m) {
            int i = threadIdx.x + m * 256;
            if (i < lim) {
                float4 v = s4[i];
                v.x = fmaxf(v.x, 0.f); v.y = fmaxf(v.y, 0.f);
                v.z = fmaxf(v.z, 0.f); v.w = fmaxf(v.w, 0.f);
                const int row = i >> 3, q = i & 7;
                sh[row * 16 + 2 * q]     = packh2(v.x, v.y);
                sh[row * 16 + 2 * q + 1] = packh2(v.z, v.w);
            }
        }
    }
    const int j = threadIdx.x & 31;
    const int r = threadIdx.x >> 5;
    const float bias = bnv[j];
    __syncthreads();

    float accA[8] = {0.f};
    float accB[8];
#pragma unroll
    for (int m = 0; m < 8; ++m) accB[m] = bias;
#pragma unroll 2
    for (int k2 = 0; k2 < 16; k2 += 4) {
        const unsigned wn0 = sWn[(k2 + 0) * 32 + j], ws0 = sWs[(k2 + 0) * 32 + j];
        const unsigned wn1 = sWn[(k2 + 1) * 32 + j], ws1 = sWs[(k2 + 1) * 32 + j];
        const unsigned wn2 = sWn[(k2 + 2) * 32 + j], ws2 = sWs[(k2 + 2) * 32 + j];
        const unsigned wn3 = sWn[(k2 + 3) * 32 + j], ws3 = sWs[(k2 + 3) * 32 + j];
#pragma unroll
        for (int m = 0; m < 8; ++m) {
            const uint4 hv = *(const uint4*)(sh + (r + 8 * m) * 16 + k2);
            accA[m] = dot2(hv.x, wn0, accA[m]);
            accA[m] = dot2(hv.y, wn1, accA[m]);
            accA[m] = dot2(hv.z, wn2, accA[m]);
            accA[m] = dot2(hv.w, wn3, accA[m]);
            accB[m] = dot2(hv.x, ws0, accB[m]);
            accB[m] = dot2(hv.y, ws1, accB[m]);
            accB[m] = dot2(hv.z, ws2, accB[m]);
            accB[m] = dot2(hv.w, ws3, accB[m]);
        }
    }
#pragma unroll
    for (int m = 0; m < 8; ++m) {
        const int node = tile + r + 8 * m;
        if (node < n_nodes) {
            Ab[(size_t)node * 32 + j] = f2fp8(accA[m]);
            HB[(size_t)node * 32 + j] = accB[m];
        }
    }
}

// ------------- Aggregation: B[n] += sum_{e in CSR[n]} A_fp8[eidx[e]] -------------
// 4 lanes per node (uint2 = 8 fp8 each), 16-edge unrolled batches, HW fp8 cvt.
__global__ __launch_bounds__(256) void k_agg2(
    const int* __restrict__ ptr, const int* __restrict__ eidx,
    const unsigned char* __restrict__ Ab, float* __restrict__ B, int n_nodes)
{
    const int g    = blockIdx.x * 64 + (threadIdx.x >> 2);
    const int lane = threadIdx.x & 3;
    if (g >= n_nodes) return;
    const int beg = ptr[g];
    const int end = ptr[g + 1];
    const uint2* __restrict__ A2 = (const uint2*)Ab;   // 8B = 8 fp8
    float4* B4 = (float4*)B;

    float4 a0 = B4[(size_t)g * 8 + lane * 2 + 0];      // cols 8l..8l+3
    float4 a1 = B4[(size_t)g * 8 + lane * 2 + 1];      // cols 8l+4..8l+7
    for (int e = beg; e < end; e += 16) {
        int idx[16];
#pragma unroll
        for (int u = 0; u < 16; ++u)
            idx[u] = (e + u < end) ? eidx[e + u] : -1;
#pragma unroll
        for (int u = 0; u < 16; ++u) {
            if (idx[u] >= 0) {
                const uint2 rw = A2[(size_t)idx[u] * 4 + lane];
                acc8_fp8(rw.x, rw.y, a0, a1);
            }
        }
    }
    B4[(size_t)g * 8 + lane * 2 + 0] = a0;
    B4[(size_t)g * 8 + lane * 2 + 1] = a1;
}

// ---------------- Zero hg ----------------
__global__ __launch_bounds__(256) void k_zero_f(float* __restrict__ p, int n)
{
    int i = blockIdx.x * 256 + threadIdx.x;
    if (i < n) p[i] = 0.f;
}

// ---------------- Node-parallel per-graph sum pool ----------------
__global__ __launch_bounds__(256) void k_pool1(
    const float* __restrict__ H, const int* __restrict__ gids,
    float* __restrict__ hg, int n_nodes)
{
    const int base = blockIdx.x * 128;
    const int lim  = min(base + 128, n_nodes);
    const int j = threadIdx.x & 31;
    const int r = threadIdx.x >> 5;

    int curg = -1;
    float acc = 0.f;
    for (int n = base + r; n < lim; n += 8) {
        const int g = gids[n];
        const float v = fmaxf(H[(size_t)n * 32 + j], 0.f);
        if (g != curg) {
            if (curg >= 0) atomicAdd(&hg[curg * 32 + j], acc);
            curg = g;
            acc = v;
        } else {
            acc += v;
        }
    }
    if (curg >= 0) atomicAdd(&hg[curg * 32 + j], acc);
}

// ---------------- FC head + softmax ----------------
__global__ __launch_bounds__(64) void k_head(
    const float* __restrict__ hg,
    const float* __restrict__ Wfc1, const float* __restrict__ bfc1,
    const float* __restrict__ Wout, const float* __restrict__ bout,
    float* __restrict__ out, int n_graphs)
{
    const int g = blockIdx.x * blockDim.x + threadIdx.x;
    if (g >= n_graphs) return;
    float h[32];
#pragma unroll
    for (int k = 0; k < 32; ++k) h[k] = hg[g * 32 + k];
    float z[8];
#pragma unroll
    for (int m = 0; m < 8; ++m) {
        float a = bfc1[m];
#pragma unroll
        for (int k = 0; k < 32; ++k) a += h[k] * Wfc1[k * 8 + m];
        z[m] = fmaxf(a, 0.f);
    }
    float o[4];
#pragma unroll
    for (int q = 0; q < 4; ++q) {
        float a = bout[q];
#pragma unroll
        for (int m = 0; m < 8; ++m) a += z[m] * Wout[m * 4 + q];
        o[q] = fmaxf(a, 0.f);
    }
    const float mx = fmaxf(fmaxf(o[0], o[1]), fmaxf(o[2], o[3]));
    const float e0 = expf(o[0] - mx), e1 = expf(o[1] - mx);
    const float e2 = expf(o[2] - mx), e3 = expf(o[3] - mx);
    const float inv = 1.f / (e0 + e1 + e2 + e3);
    out[g * 4 + 0] = e0 * inv;
    out[g * 4 + 1] = e1 * inv;
    out[g * 4 + 2] = e2 * inv;
    out[g * 4 + 3] = e3 * inv;
}

extern "C" void kernel_launch(void* const* d_in, const int* in_sizes, int n_in,
                              void* d_out, int out_size, void* d_ws, size_t ws_size,
                              hipStream_t stream)
{
    const float* x    = (const float*)d_in[0];
    const float* Wn0  = (const float*)d_in[1];
    const float* bn0  = (const float*)d_in[2];
    const float* Ws0  = (const float*)d_in[3];
    const float* Wn   = (const float*)d_in[4];   // [3,32,32]
    const float* bn   = (const float*)d_in[5];   // [3,32]
    const float* Ws   = (const float*)d_in[6];   // [3,32,32]
    const float* Wfc1 = (const float*)d_in[7];
    const float* bfc1 = (const float*)d_in[8];
    const float* Wout = (const float*)d_in[9];
    const float* bout = (const float*)d_in[10];
    const int*   src  = (const int*)d_in[11];
    const int*   dst  = (const int*)d_in[12];
    const int*   gids = (const int*)d_in[13];

    const int n_nodes  = in_sizes[0] / 128;
    const int n_edges  = in_sizes[11];
    const int n_graphs = out_size / 4;
    const size_t N32 = (size_t)n_nodes * 32;

    const int NB = (n_nodes + TILE_NODES - 1) / TILE_NODES;
    const int C  = (n_edges + CE - 1) / CE;
    const int n_off = NB * C;

    unsigned char* Ab = (unsigned char*)d_ws;            // [N,32] fp8 (N32 bytes)
    float* B   = (float*)(Ab + N32);                     // [N,32] fp32 (in-place)
    float* hg  = B + N32;                                // [G,32]
    int* histT = (int*)(hg + (size_t)n_graphs * 32);     // [NB*C]
    int* off   = histT + n_off;                          // [NB*C + 1]
    int* part  = off + n_off + 1;                        // [<=256]
    int* ptr   = part + 256;                             // [N+1]
    unsigned int* ebuf = (unsigned int*)(ptr + n_nodes + 1);  // [E]
    int* eidx  = (int*)(ebuf + n_edges);                 // [E]

    const int nparts = (n_off + SCAN_CHUNK - 1) / SCAN_CHUNK;

    // ---- edge sort (once per call; reused by all 4 layers) ----
    k_hist2<<<C, 1024, 0, stream>>>(dst, histT, n_edges, NB, C);
    k_chunk_sum<<<nparts, 256, 0, stream>>>(histT, part, n_off);
    k_scan_part<<<1, 64, 0, stream>>>(part, nparts);
    k_write_off<<<nparts, 256, 0, stream>>>(histT, part, off, n_off, n_edges);
    k_binfill<<<C, 1024, 0, stream>>>(src, dst, off, ebuf, n_edges, NB, C);
    k_tile_sort<<<NB, 1024, 0, stream>>>(off, ebuf, eidx, ptr, n_nodes, NB, C, n_edges);

    const int mblocks0 = (n_nodes + 31) / 32;
    const int mblocks  = (n_nodes + 63) / 64;
    const int ablocks  = (n_nodes + 63) / 64;

    // ---- Layer 0 ----
    k_layer0<<<mblocks0, 256, 0, stream>>>(x, Wn0, bn0, Ws0, Ab, B, n_nodes);
    k_agg2<<<ablocks, 256, 0, stream>>>(ptr, eidx, Ab, B, n_nodes);

    // ---- Layers 1..3 (in-place on B) ----
    for (int l = 0; l < 3; ++l) {
        k_layer<<<mblocks, 256, 0, stream>>>(B, Wn + l * 1024, bn + l * 32,
                                             Ws + l * 1024, Ab, n_nodes);
        k_agg2<<<ablocks, 256, 0, stream>>>(ptr, eidx, Ab, B, n_nodes);
    }

    // ---- Pool + head ----
    k_zero_f<<<(n_graphs * 32 + 255) / 256, 256, 0, stream>>>(hg, n_graphs * 32);
    k_pool1<<<(n_nodes + 127) / 128, 256, 0, stream>>>(B, gids, hg, n_nodes);
    k_head<<<(n_graphs + 63) / 64, 64, 0, stream>>>(hg, Wfc1, bfc1, Wout, bout,
                                                    (float*)d_out, n_graphs);
}

// Round 12
// 367.571 us; speedup vs baseline: 1.4748x; 1.0744x over previous
//
#include <hip/hip_runtime.h>
#include <hip/hip_bf16.h>
#include <math.h>

// GCN forward: 4 GraphConv layers + sum-pool + FC head + softmax.
// N_NODES=100000, N_EDGES=3200000, N_GRAPHS=64, IN=128, DIM=32.
//
// Round-12 (= round-11 + padded-CSR aggregation):
//  - eidx segments per node padded to x4 with sentinel rows (zero row in Ab
//    at index 131071); agg loads indices as int4 (4 edges/load, no per-edge
//    guards), 16-edge unguarded main loop -> 4x fewer index loads, clean MLP.
//  - A stays fp8 e4m3fn (L2-resident); f16 dot2 transforms with
//    __launch_bounds__(256,4) register cap.

#define TILE_NODES 256
#define CE 12800                 // edges per sort chunk
#define SCAN_CHUNK 2048
#define MAX_NB 1024
#define SENT 131071              // sentinel node index (zero row in Ab)

// ---- fp8 e4m3fn software encode (RTN-even) ----
__device__ inline unsigned char f2fp8(float f) {
    unsigned u = __float_as_uint(f);
    unsigned s = (u >> 24) & 0x80u;
    float a = fminf(fabsf(f), 448.f);
    unsigned v = __float_as_uint(a * 0x1p-120f);   // e4m3 window -> f32 exp field
    v = v + 0xFFFFFu + ((v >> 20) & 1u);           // RTN-even to 3 mantissa bits
    return (unsigned char)(s | ((v >> 20) & 0x7Fu));
}
__device__ inline float fp8_dec(unsigned x) {      // one byte, software fallback
    unsigned v = ((x & 0x80u) << 24) | ((x & 0x7Fu) << 20);
    return __uint_as_float(v) * 0x1p120f;
}

typedef float v2f __attribute__((ext_vector_type(2)));
typedef _Float16 h2 __attribute__((ext_vector_type(2)));
typedef __fp16 p2 __attribute__((ext_vector_type(2)));
union U32H2 { unsigned u; h2 h; p2 p; };

__device__ inline unsigned packh2(float a, float b) {
#if __has_builtin(__builtin_amdgcn_cvt_pkrtz)
    U32H2 t; t.p = __builtin_amdgcn_cvt_pkrtz(a, b); return t.u;
#else
    U32H2 t; t.h.x = (_Float16)a; t.h.y = (_Float16)b; return t.u;
#endif
}
__device__ inline float dot2(unsigned a, unsigned b, float c) {
    U32H2 ua, ub; ua.u = a; ub.u = b;
#if __has_builtin(__builtin_amdgcn_fdot2)
    return __builtin_amdgcn_fdot2(ua.h, ub.h, c, false);
#else
    return c + (float)ua.h.x * (float)ub.h.x + (float)ua.h.y * (float)ub.h.y;
#endif
}

// accumulate 8 fp8 (two dwords) into two float4 accumulators
__device__ inline void acc8_fp8(unsigned w0, unsigned w1, float4& a0, float4& a1) {
#if __has_builtin(__builtin_amdgcn_cvt_pk_f32_fp8)
    v2f p0 = __builtin_amdgcn_cvt_pk_f32_fp8(w0, 0);
    v2f p1 = __builtin_amdgcn_cvt_pk_f32_fp8(w0, 1);
    v2f p2v = __builtin_amdgcn_cvt_pk_f32_fp8(w1, 0);
    v2f p3 = __builtin_amdgcn_cvt_pk_f32_fp8(w1, 1);
    a0.x += p0.x; a0.y += p0.y; a0.z += p1.x; a0.w += p1.y;
    a1.x += p2v.x; a1.y += p2v.y; a1.z += p3.x; a1.w += p3.y;
#else
    a0.x += fp8_dec(w0 & 0xFFu);         a0.y += fp8_dec((w0 >> 8) & 0xFFu);
    a0.z += fp8_dec((w0 >> 16) & 0xFFu); a0.w += fp8_dec(w0 >> 24);
    a1.x += fp8_dec(w1 & 0xFFu);         a1.y += fp8_dec((w1 >> 8) & 0xFFu);
    a1.z += fp8_dec((w1 >> 16) & 0xFFu); a1.w += fp8_dec(w1 >> 24);
#endif
}

// ---------------- Pass 1: per-chunk histogram over dst tiles ----------------
__global__ __launch_bounds__(1024) void k_hist2(
    const int* __restrict__ dst, int* __restrict__ histT,
    int n_edges, int NB, int C)
{
    __shared__ int hist[MAX_NB];
    const int c = blockIdx.x;
    for (int b = threadIdx.x; b < NB; b += 1024) hist[b] = 0;
    __syncthreads();
    const int beg = c * CE;
    const int end = min(beg + CE, n_edges);
    for (int e = beg + threadIdx.x; e < end; e += 1024)
        atomicAdd(&hist[dst[e] >> 8], 1);
    __syncthreads();
    for (int b = threadIdx.x; b < NB; b += 1024)
        histT[b * C + c] = hist[b];
}

// ---------------- Pass 2: hierarchical exclusive scan of histT ----------------
__global__ __launch_bounds__(256) void k_chunk_sum(
    const int* __restrict__ v, int* __restrict__ part, int n)
{
    __shared__ int red[256];
    const int base = blockIdx.x * SCAN_CHUNK;
    int s = 0;
    for (int i = threadIdx.x; i < SCAN_CHUNK; i += 256) {
        int idx = base + i;
        if (idx < n) s += v[idx];
    }
    red[threadIdx.x] = s;
    __syncthreads();
    for (int off = 128; off > 0; off >>= 1) {
        if (threadIdx.x < off) red[threadIdx.x] += red[threadIdx.x + off];
        __syncthreads();
    }
    if (threadIdx.x == 0) part[blockIdx.x] = red[0];
}

__global__ void k_scan_part(int* __restrict__ part, int nparts)
{
    if (threadIdx.x == 0 && blockIdx.x == 0) {
        int run = 0;
        for (int i = 0; i < nparts; ++i) { int v = part[i]; part[i] = run; run += v; }
    }
}

__global__ __launch_bounds__(256) void k_write_off(
    const int* __restrict__ v, const int* __restrict__ part,
    int* __restrict__ off, int n, int total)
{
    __shared__ int lds[256];
    const int tid   = threadIdx.x;
    const int base  = blockIdx.x * SCAN_CHUNK;
    const int tbase = base + tid * 8;
    int c[8];
    int tot = 0;
#pragma unroll
    for (int m = 0; m < 8; ++m) {
        int idx = tbase + m;
        c[m] = (idx < n) ? v[idx] : 0;
        tot += c[m];
    }
    lds[tid] = tot;
    __syncthreads();
    for (int o = 1; o < 256; o <<= 1) {
        int val = (tid >= o) ? lds[tid - o] : 0;
        __syncthreads();
        lds[tid] += val;
        __syncthreads();
    }
    int run = part[blockIdx.x] + lds[tid] - tot;
#pragma unroll
    for (int m = 0; m < 8; ++m) {
        int idx = tbase + m;
        if (idx < n) off[idx] = run;
        run += c[m];
    }
    if (blockIdx.x == 0 && tid == 0) off[n] = total;
}

// ---------------- Pass 3: bin packed edges into tile regions ----------------
__global__ __launch_bounds__(1024) void k_binfill(
    const int* __restrict__ src, const int* __restrict__ dst,
    const int* __restrict__ off, unsigned int* __restrict__ ebuf,
    int n_edges, int NB, int C)
{
    __shared__ int lcur[MAX_NB];
    const int c = blockIdx.x;
    for (int b = threadIdx.x; b < NB; b += 1024)
        lcur[b] = off[b * C + c];
    __syncthreads();
    const int beg = c * CE;
    const int end = min(beg + CE, n_edges);
    for (int e = beg + threadIdx.x; e < end; e += 1024) {
        const int d = dst[e];
        const int b = d >> 8;
        const unsigned int dl = (unsigned int)(d & 255);
        const int pos = atomicAdd(&lcur[b], 1);
        ebuf[pos] = (dl << 17) | (unsigned int)src[e];
    }
}

// ---- Pass 4: per-tile counting sort -> padded eidx + ptrb/ptre ----
// Each node's segment padded to x4 with SENT; tile base 4-aligned with
// +1024-per-tile slack in eidx.
__global__ __launch_bounds__(1024) void k_tile_sort(
    const int* __restrict__ off, const unsigned int* __restrict__ ebuf,
    int* __restrict__ eidx, int* __restrict__ ptrb, int* __restrict__ ptre,
    int n_nodes, int NB, int C, int n_edges)
{
    __shared__ int hist[TILE_NODES];
    __shared__ int phist[TILE_NODES];
    __shared__ int scan[TILE_NODES];
    __shared__ int cur[TILE_NODES];
    const int t = blockIdx.x;
    const int beg = off[t * C];
    const int end = (t + 1 < NB) ? off[(t + 1) * C] : n_edges;
    const int tb  = ((beg + 3) & ~3) + 1024 * t;      // padded, 4-aligned base
    const int node_base = t * TILE_NODES;
    const int n_valid = min(TILE_NODES, n_nodes - node_base);

    if (threadIdx.x < TILE_NODES) hist[threadIdx.x] = 0;
    __syncthreads();
    for (int e = beg + threadIdx.x; e < end; e += 1024)
        atomicAdd(&hist[ebuf[e] >> 17], 1);
    __syncthreads();
    if (threadIdx.x < TILE_NODES) {
        const int ph = (hist[threadIdx.x] + 3) & ~3;
        phist[threadIdx.x] = ph;
        scan[threadIdx.x]  = ph;
    }
    __syncthreads();
    for (int o = 1; o < TILE_NODES; o <<= 1) {
        int v = 0;
        if (threadIdx.x < TILE_NODES && threadIdx.x >= o) v = scan[threadIdx.x - o];
        __syncthreads();
        if (threadIdx.x < TILE_NODES) scan[threadIdx.x] += v;
        __syncthreads();
    }
    if (threadIdx.x < TILE_NODES) {
        const int ex = scan[threadIdx.x] - phist[threadIdx.x];   // exclusive
        cur[threadIdx.x] = ex;
        if (threadIdx.x < n_valid) {
            ptrb[node_base + threadIdx.x] = tb + ex;
            ptre[node_base + threadIdx.x] = tb + ex + phist[threadIdx.x];
        }
    }
    __syncthreads();
    for (int e = beg + threadIdx.x; e < end; e += 1024) {
        const unsigned int v = ebuf[e];
        const int dl = (int)(v >> 17);
        const int pos = tb + atomicAdd(&cur[dl], 1);
        eidx[pos] = (int)(v & 0x1FFFFu);
    }
    __syncthreads();
    // fill pads [hist, phist) with SENT
    if (threadIdx.x < n_valid) {
        int p  = tb + cur[threadIdx.x];                     // = ex + hist
        const int pe = tb + scan[threadIdx.x];              // = ex + phist
        for (; p < pe; ++p) eidx[p] = SENT;
    }
}

// ---------------- Layer 0: A(fp8) = x@Wn0 ; B = x@Ws0 + bn0 ----------------
__global__ __launch_bounds__(256, 4) void k_layer0(
    const float* __restrict__ x, const float* __restrict__ Wn0,
    const float* __restrict__ bn0, const float* __restrict__ Ws0,
    unsigned char* __restrict__ Ab, float* __restrict__ B, int n_nodes)
{
    __shared__ unsigned sWn[64 * 32];   // [k2][j]
    __shared__ unsigned sWs[64 * 32];
    __shared__ unsigned sx[32 * 64];    // [row][k2]

    for (int i = threadIdx.x; i < 64 * 32; i += 256) {
        const int k2 = i >> 5, jj = i & 31;
        sWn[i] = packh2(Wn0[(2 * k2) * 32 + jj], Wn0[(2 * k2 + 1) * 32 + jj]);
        sWs[i] = packh2(Ws0[(2 * k2) * 32 + jj], Ws0[(2 * k2 + 1) * 32 + jj]);
    }
    const int tile = blockIdx.x * 32;
    {
        const float4* s4 = (const float4*)(x + (size_t)tile * 128);
        const int lim = (n_nodes - tile) * 32;   // float4 count
#pragma unroll
        for (int m = 0; m < 4; ++m) {
            int i = threadIdx.x + m * 256;
            if (i < lim) {
                float4 v = s4[i];
                const int row = i >> 5, q = i & 31;
                sx[row * 64 + 2 * q]     = packh2(v.x, v.y);
                sx[row * 64 + 2 * q + 1] = packh2(v.z, v.w);
            }
        }
    }
    const int j = threadIdx.x & 31;
    const int r = threadIdx.x >> 5;
    const float bias = bn0[j];
    __syncthreads();

    float accA[4] = {0.f, 0.f, 0.f, 0.f};
    float accB[4] = {bias, bias, bias, bias};
#pragma unroll 2
    for (int k2 = 0; k2 < 64; k2 += 4) {
        const unsigned wn0 = sWn[(k2 + 0) * 32 + j], ws0 = sWs[(k2 + 0) * 32 + j];
        const unsigned wn1 = sWn[(k2 + 1) * 32 + j], ws1 = sWs[(k2 + 1) * 32 + j];
        const unsigned wn2 = sWn[(k2 + 2) * 32 + j], ws2 = sWs[(k2 + 2) * 32 + j];
        const unsigned wn3 = sWn[(k2 + 3) * 32 + j], ws3 = sWs[(k2 + 3) * 32 + j];
#pragma unroll
        for (int m = 0; m < 4; ++m) {
            const uint4 xv = *(const uint4*)(sx + (r + 8 * m) * 64 + k2);
            accA[m] = dot2(xv.x, wn0, accA[m]);
            accA[m] = dot2(xv.y, wn1, accA[m]);
            accA[m] = dot2(xv.z, wn2, accA[m]);
            accA[m] = dot2(xv.w, wn3, accA[m]);
            accB[m] = dot2(xv.x, ws0, accB[m]);
            accB[m] = dot2(xv.y, ws1, accB[m]);
            accB[m] = dot2(xv.z, ws2, accB[m]);
            accB[m] = dot2(xv.w, ws3, accB[m]);
        }
    }
#pragma unroll
    for (int m = 0; m < 4; ++m) {
        const int node = tile + r + 8 * m;
        if (node < n_nodes) {
            Ab[(size_t)node * 32 + j] = f2fp8(accA[m]);
            B[(size_t)node * 32 + j] = accB[m];
        }
    }
}

// ------------- Layers 1..3 (in-place on B): A(fp8) = relu(B)@Wn ; B = relu(B)@Ws + bn -------------
__global__ __launch_bounds__(256, 4) void k_layer(
    float* HB,                       // read pre-act, overwritten with new B
    const float* __restrict__ Wn, const float* __restrict__ bnv,
    const float* __restrict__ Ws, unsigned char* __restrict__ Ab, int n_nodes)
{
    __shared__ unsigned sWn[16 * 32];   // [k2][j]
    __shared__ unsigned sWs[16 * 32];
    __shared__ unsigned sh[64 * 16];    // [row][k2]

    for (int i = threadIdx.x; i < 16 * 32; i += 256) {
        const int k2 = i >> 5, jj = i & 31;
        sWn[i] = packh2(Wn[(2 * k2) * 32 + jj], Wn[(2 * k2 + 1) * 32 + jj]);
        sWs[i] = packh2(Ws[(2 * k2) * 32 + jj], Ws[(2 * k2 + 1) * 32 + jj]);
    }
    const int tile = blockIdx.x * 64;
    {
        const float4* s4 = (const float4*)(HB + (size_t)tile * 32);
        const int lim = (n_nodes - tile) * 8;   // float4 count
#pragma unroll
        for (int m = 0; m < 2; ++m) {
            int i = threadIdx.x + m * 256;
            if (i < lim) {
                float4 v = s4[i];
                v.x = fmaxf(v.x, 0.f); v.y = fmaxf(v.y, 0.f);
                v.z = fmaxf(v.z, 0.f); v.w = fmaxf(v.w, 0.f);
                const int row = i >> 3, q = i & 7;
                sh[row * 16 + 2 * q]     = packh2(v.x, v.y);
                sh[row * 16 + 2 * q + 1] = packh2(v.z, v.w);
            }
        }
    }
    const int j = threadIdx.x & 31;
    const int r = threadIdx.x >> 5;
    const float bias = bnv[j];
    __syncthreads();

    float accA[8] = {0.f};
    float accB[8];
#pragma unroll
    for (int m = 0; m < 8; ++m) accB[m] = bias;
#pragma unroll 2
    for (int k2 = 0; k2 < 16; k2 += 4) {
        const unsigned wn0 = sWn[(k2 + 0) * 32 + j], ws0 = sWs[(k2 + 0) * 32 + j];
        const unsigned wn1 = sWn[(k2 + 1) * 32 + j], ws1 = sWs[(k2 + 1) * 32 + j];
        const unsigned wn2 = sWn[(k2 + 2) * 32 + j], ws2 = sWs[(k2 + 2) * 32 + j];
        const unsigned wn3 = sWn[(k2 + 3) * 32 + j], ws3 = sWs[(k2 + 3) * 32 + j];
#pragma unroll
        for (int m = 0; m < 8; ++m) {
            const uint4 hv = *(const uint4*)(sh + (r + 8 * m) * 16 + k2);
            accA[m] = dot2(hv.x, wn0, accA[m]);
            accA[m] = dot2(hv.y, wn1, accA[m]);
            accA[m] = dot2(hv.z, wn2, accA[m]);
            accA[m] = dot2(hv.w, wn3, accA[m]);
            accB[m] = dot2(hv.x, ws0, accB[m]);
            accB[m] = dot2(hv.y, ws1, accB[m]);
            accB[m] = dot2(hv.z, ws2, accB[m]);
            accB[m] = dot2(hv.w, ws3, accB[m]);
        }
    }
#pragma unroll
    for (int m = 0; m < 8; ++m) {
        const int node = tile + r + 8 * m;
        if (node < n_nodes) {
            Ab[(size_t)node * 32 + j] = f2fp8(accA[m]);
            HB[(size_t)node * 32 + j] = accB[m];
        }
    }
}

// ------------- Aggregation: B[n] += sum_{e in padded CSR[n]} A_fp8[eidx[e]] -------------
// 4 lanes/node; int4 index loads (4 edges, no per-edge guard); 16-edge main loop.
__global__ __launch_bounds__(256) void k_agg3(
    const int* __restrict__ ptrb, const int* __restrict__ ptre,
    const int* __restrict__ eidx,
    const unsigned char* __restrict__ Ab, float* __restrict__ B, int n_nodes)
{
    const int g    = blockIdx.x * 64 + (threadIdx.x >> 2);
    const int lane = threadIdx.x & 3;
    if (g >= n_nodes) return;
    const int beg = ptrb[g];
    const int end = ptre[g];
    const uint2* __restrict__ A2 = (const uint2*)Ab;   // 8B = 8 fp8
    const int4* __restrict__ E4 = (const int4*)eidx;   // beg is 4-aligned
    float4* B4 = (float4*)B;

    float4 a0 = B4[(size_t)g * 8 + lane * 2 + 0];      // cols 8l..8l+3
    float4 a1 = B4[(size_t)g * 8 + lane * 2 + 1];      // cols 8l+4..8l+7
    int e4 = beg >> 2;
    const int n4 = end >> 2;
    // main loop: 16 edges, fully unguarded
    for (; e4 + 4 <= n4; e4 += 4) {
        const int4 q0 = E4[e4 + 0];
        const int4 q1 = E4[e4 + 1];
        const int4 q2 = E4[e4 + 2];
        const int4 q3 = E4[e4 + 3];
        uint2 rw;
        rw = A2[(size_t)q0.x * 4 + lane]; acc8_fp8(rw.x, rw.y, a0, a1);
        rw = A2[(size_t)q0.y * 4 + lane]; acc8_fp8(rw.x, rw.y, a0, a1);
        rw = A2[(size_t)q0.z * 4 + lane]; acc8_fp8(rw.x, rw.y, a0, a1);
        rw = A2[(size_t)q0.w * 4 + lane]; acc8_fp8(rw.x, rw.y, a0, a1);
        rw = A2[(size_t)q1.x * 4 + lane]; acc8_fp8(rw.x, rw.y, a0, a1);
        rw = A2[(size_t)q1.y * 4 + lane]; acc8_fp8(rw.x, rw.y, a0, a1);
        rw = A2[(size_t)q1.z * 4 + lane]; acc8_fp8(rw.x, rw.y, a0, a1);
        rw = A2[(size_t)q1.w * 4 + lane]; acc8_fp8(rw.x, rw.y, a0, a1);
        rw = A2[(size_t)q2.x * 4 + lane]; acc8_fp8(rw.x, rw.y, a0, a1);
        rw = A2[(size_t)q2.y * 4 + lane]; acc8_fp8(rw.x, rw.y, a0, a1);
        rw = A2[(size_t)q2.z * 4 + lane]; acc8_fp8(rw.x, rw.y, a0, a1);
        rw = A2[(size_t)q2.w * 4 + lane]; acc8_fp8(rw.x, rw.y, a0, a1);
        rw = A2[(size_t)q3.x * 4 + lane]; acc8_fp8(rw.x, rw.y, a0, a1);
        rw = A2[(size_t)q3.y * 4 + lane]; acc8_fp8(rw.x, rw.y, a0, a1);
        rw = A2[(size_t)q3.z * 4 + lane]; acc8_fp8(rw.x, rw.y, a0, a1);
        rw = A2[(size_t)q3.w * 4 + lane]; acc8_fp8(rw.x, rw.y, a0, a1);
    }
    // tail: int4 granularity (segments are padded to x4 with SENT)
    for (; e4 < n4; ++e4) {
        const int4 q = E4[e4];
        uint2 rw;
        rw = A2[(size_t)q.x * 4 + lane]; acc8_fp8(rw.x, rw.y, a0, a1);
        rw = A2[(size_t)q.y * 4 + lane]; acc8_fp8(rw.x, rw.y, a0, a1);
        rw = A2[(size_t)q.z * 4 + lane]; acc8_fp8(rw.x, rw.y, a0, a1);
        rw = A2[(size_t)q.w * 4 + lane]; acc8_fp8(rw.x, rw.y, a0, a1);
    }
    B4[(size_t)g * 8 + lane * 2 + 0] = a0;
    B4[(size_t)g * 8 + lane * 2 + 1] = a1;
}

// ---------------- Zero helper ----------------
__global__ __launch_bounds__(256) void k_zero_f(float* __restrict__ p, int n)
{
    int i = blockIdx.x * 256 + threadIdx.x;
    if (i < n) p[i] = 0.f;
}

// ---------------- Node-parallel per-graph sum pool ----------------
__global__ __launch_bounds__(256) void k_pool1(
    const float* __restrict__ H, const int* __restrict__ gids,
    float* __restrict__ hg, int n_nodes)
{
    const int base = blockIdx.x * 128;
    const int lim  = min(base + 128, n_nodes);
    const int j = threadIdx.x & 31;
    const int r = threadIdx.x >> 5;

    int curg = -1;
    float acc = 0.f;
    for (int n = base + r; n < lim; n += 8) {
        const int g = gids[n];
        const float v = fmaxf(H[(size_t)n * 32 + j], 0.f);
        if (g != curg) {
            if (curg >= 0) atomicAdd(&hg[curg * 32 + j], acc);
            curg = g;
            acc = v;
        } else {
            acc += v;
        }
    }
    if (curg >= 0) atomicAdd(&hg[curg * 32 + j], acc);
}

// ---------------- FC head + softmax ----------------
__global__ __launch_bounds__(64) void k_head(
    const float* __restrict__ hg,
    const float* __restrict__ Wfc1, const float* __restrict__ bfc1,
    const float* __restrict__ Wout, const float* __restrict__ bout,
    float* __restrict__ out, int n_graphs)
{
    const int g = blockIdx.x * blockDim.x + threadIdx.x;
    if (g >= n_graphs) return;
    float h[32];
#pragma unroll
    for (int k = 0; k < 32; ++k) h[k] = hg[g * 32 + k];
    float z[8];
#pragma unroll
    for (int m = 0; m < 8; ++m) {
        float a = bfc1[m];
#pragma unroll
        for (int k = 0; k < 32; ++k) a += h[k] * Wfc1[k * 8 + m];
        z[m] = fmaxf(a, 0.f);
    }
    float o[4];
#pragma unroll
    for (int q = 0; q < 4; ++q) {
        float a = bout[q];
#pragma unroll
        for (int m = 0; m < 8; ++m) a += z[m] * Wout[m * 4 + q];
        o[q] = fmaxf(a, 0.f);
    }
    const float mx = fmaxf(fmaxf(o[0], o[1]), fmaxf(o[2], o[3]));
    const float e0 = expf(o[0] - mx), e1 = expf(o[1] - mx);
    const float e2 = expf(o[2] - mx), e3 = expf(o[3] - mx);
    const float inv = 1.f / (e0 + e1 + e2 + e3);
    out[g * 4 + 0] = e0 * inv;
    out[g * 4 + 1] = e1 * inv;
    out[g * 4 + 2] = e2 * inv;
    out[g * 4 + 3] = e3 * inv;
}

extern "C" void kernel_launch(void* const* d_in, const int* in_sizes, int n_in,
                              void* d_out, int out_size, void* d_ws, size_t ws_size,
                              hipStream_t stream)
{
    const float* x    = (const float*)d_in[0];
    const float* Wn0  = (const float*)d_in[1];
    const float* bn0  = (const float*)d_in[2];
    const float* Ws0  = (const float*)d_in[3];
    const float* Wn   = (const float*)d_in[4];   // [3,32,32]
    const float* bn   = (const float*)d_in[5];   // [3,32]
    const float* Ws   = (const float*)d_in[6];   // [3,32,32]
    const float* Wfc1 = (const float*)d_in[7];
    const float* bfc1 = (const float*)d_in[8];
    const float* Wout = (const float*)d_in[9];
    const float* bout = (const float*)d_in[10];
    const int*   src  = (const int*)d_in[11];
    const int*   dst  = (const int*)d_in[12];
    const int*   gids = (const int*)d_in[13];

    const int n_nodes  = in_sizes[0] / 128;
    const int n_edges  = in_sizes[11];
    const int n_graphs = out_size / 4;
    const size_t N32 = (size_t)n_nodes * 32;
    const size_t AB_ROWS = 131072;               // 1<<17 rows (SENT = last)

    const int NB = (n_nodes + TILE_NODES - 1) / TILE_NODES;
    const int C  = (n_edges + CE - 1) / CE;
    const int n_off = NB * C;

    unsigned char* Ab = (unsigned char*)d_ws;            // [AB_ROWS,32] fp8
    float* B   = (float*)(Ab + AB_ROWS * 32);            // [N,32] fp32 (in-place)
    float* hg  = B + N32;                                // [G,32]
    int* histT = (int*)(hg + (size_t)n_graphs * 32);     // [NB*C]
    int* off   = histT + n_off;                          // [NB*C + 1]
    int* part  = off + n_off + 1;                        // [<=256]
    int* ptrb  = part + 256;                             // [N]
    int* ptre  = ptrb + n_nodes;                         // [N]
    unsigned int* ebuf = (unsigned int*)(ptre + n_nodes);     // [E]
    int* eidx  = (int*)(ebuf + n_edges);                 // [E + 1024*NB + 4]

    const int nparts = (n_off + SCAN_CHUNK - 1) / SCAN_CHUNK;

    // ---- edge sort (once per call; reused by all 4 layers) ----
    k_hist2<<<C, 1024, 0, stream>>>(dst, histT, n_edges, NB, C);
    k_chunk_sum<<<nparts, 256, 0, stream>>>(histT, part, n_off);
    k_scan_part<<<1, 64, 0, stream>>>(part, nparts);
    k_write_off<<<nparts, 256, 0, stream>>>(histT, part, off, n_off, n_edges);
    k_binfill<<<C, 1024, 0, stream>>>(src, dst, off, ebuf, n_edges, NB, C);
    k_tile_sort<<<NB, 1024, 0, stream>>>(off, ebuf, eidx, ptrb, ptre,
                                         n_nodes, NB, C, n_edges);
    // zero the sentinel row of Ab (32 bytes = 8 floats)
    k_zero_f<<<1, 256, 0, stream>>>((float*)(Ab + (size_t)SENT * 32), 8);

    const int mblocks0 = (n_nodes + 31) / 32;
    const int mblocks  = (n_nodes + 63) / 64;
    const int ablocks  = (n_nodes + 63) / 64;

    // ---- Layer 0 ----
    k_layer0<<<mblocks0, 256, 0, stream>>>(x, Wn0, bn0, Ws0, Ab, B, n_nodes);
    k_agg3<<<ablocks, 256, 0, stream>>>(ptrb, ptre, eidx, Ab, B, n_nodes);

    // ---- Layers 1..3 (in-place on B) ----
    for (int l = 0; l < 3; ++l) {
        k_layer<<<mblocks, 256, 0, stream>>>(B, Wn + l * 1024, bn + l * 32,
                                             Ws + l * 1024, Ab, n_nodes);
        k_agg3<<<ablocks, 256, 0, stream>>>(ptrb, ptre, eidx, Ab, B, n_nodes);
    }

    // ---- Pool + head ----
    k_zero_f<<<(n_graphs * 32 + 255) / 256, 256, 0, stream>>>(hg, n_graphs * 32);
    k_pool1<<<(n_nodes + 127) / 128, 256, 0, stream>>>(B, gids, hg, n_nodes);
    k_head<<<(n_graphs + 63) / 64, 64, 0, stream>>>(hg, Wfc1, bfc1, Wout, bout,
                                                    (float*)d_out, n_graphs);
}

// Round 13
// 348.509 us; speedup vs baseline: 1.5555x; 1.0547x over previous
//
#include <hip/hip_runtime.h>
#include <hip/hip_bf16.h>
#include <math.h>

// GCN forward: 4 GraphConv layers + sum-pool + FC head + softmax.
// N_NODES=100000, N_EDGES=3200000, N_GRAPHS=64, IN=128, DIM=32.
//
// Round-13 (= round-12 + MFMA transform kernels):
//  - k_layer0/k_layer use v_mfma_f32_16x16x32_f16. x/H staged in LDS as f16
//    (chunk-XOR swizzle for bank balance); weights pre-swizzled once per call
//    into fragment-ordered f16 buffers (k_wprep) -> coalesced L2-hit loads.
//  - A stays fp8 e4m3fn (3.2 MB, per-XCD-L2-resident); padded-CSR int4 agg.

#define TILE_NODES 256
#define CE 12800                 // edges per sort chunk
#define SCAN_CHUNK 2048
#define MAX_NB 1024
#define SENT 131071              // sentinel node index (zero row in Ab)

// ---- fp8 e4m3fn software encode (RTN-even) ----
__device__ inline unsigned char f2fp8(float f) {
    unsigned u = __float_as_uint(f);
    unsigned s = (u >> 24) & 0x80u;
    float a = fminf(fabsf(f), 448.f);
    unsigned v = __float_as_uint(a * 0x1p-120f);   // e4m3 window -> f32 exp field
    v = v + 0xFFFFFu + ((v >> 20) & 1u);           // RTN-even to 3 mantissa bits
    return (unsigned char)(s | ((v >> 20) & 0x7Fu));
}
__device__ inline float fp8_dec(unsigned x) {      // one byte, software fallback
    unsigned v = ((x & 0x80u) << 24) | ((x & 0x7Fu) << 20);
    return __uint_as_float(v) * 0x1p120f;
}

typedef float v2f __attribute__((ext_vector_type(2)));
typedef _Float16 h2 __attribute__((ext_vector_type(2)));
typedef __fp16 p2 __attribute__((ext_vector_type(2)));
typedef _Float16 f16x8 __attribute__((ext_vector_type(8)));
typedef float f32x4v __attribute__((ext_vector_type(4)));
union U32H2 { unsigned u; h2 h; p2 p; };
union UF { uint4 u; f16x8 h; };

__device__ inline unsigned packh2(float a, float b) {
#if __has_builtin(__builtin_amdgcn_cvt_pkrtz)
    U32H2 t; t.p = __builtin_amdgcn_cvt_pkrtz(a, b); return t.u;
#else
    U32H2 t; t.h.x = (_Float16)a; t.h.y = (_Float16)b; return t.u;
#endif
}

// accumulate 8 fp8 (two dwords) into two float4 accumulators
__device__ inline void acc8_fp8(unsigned w0, unsigned w1, float4& a0, float4& a1) {
#if __has_builtin(__builtin_amdgcn_cvt_pk_f32_fp8)
    v2f p0 = __builtin_amdgcn_cvt_pk_f32_fp8(w0, 0);
    v2f p1 = __builtin_amdgcn_cvt_pk_f32_fp8(w0, 1);
    v2f p2v = __builtin_amdgcn_cvt_pk_f32_fp8(w1, 0);
    v2f p3 = __builtin_amdgcn_cvt_pk_f32_fp8(w1, 1);
    a0.x += p0.x; a0.y += p0.y; a0.z += p1.x; a0.w += p1.y;
    a1.x += p2v.x; a1.y += p2v.y; a1.z += p3.x; a1.w += p3.y;
#else
    a0.x += fp8_dec(w0 & 0xFFu);         a0.y += fp8_dec((w0 >> 8) & 0xFFu);
    a0.z += fp8_dec((w0 >> 16) & 0xFFu); a0.w += fp8_dec(w0 >> 24);
    a1.x += fp8_dec(w1 & 0xFFu);         a1.y += fp8_dec((w1 >> 8) & 0xFFu);
    a1.z += fp8_dec((w1 >> 16) & 0xFFu); a1.w += fp8_dec(w1 >> 24);
#endif
}

// ---------------- Pass 1: per-chunk histogram over dst tiles ----------------
__global__ __launch_bounds__(1024) void k_hist2(
    const int* __restrict__ dst, int* __restrict__ histT,
    int n_edges, int NB, int C)
{
    __shared__ int hist[MAX_NB];
    const int c = blockIdx.x;
    for (int b = threadIdx.x; b < NB; b += 1024) hist[b] = 0;
    __syncthreads();
    const int beg = c * CE;
    const int end = min(beg + CE, n_edges);
    for (int e = beg + threadIdx.x; e < end; e += 1024)
        atomicAdd(&hist[dst[e] >> 8], 1);
    __syncthreads();
    for (int b = threadIdx.x; b < NB; b += 1024)
        histT[b * C + c] = hist[b];
}

// ---------------- Pass 2: hierarchical exclusive scan of histT ----------------
__global__ __launch_bounds__(256) void k_chunk_sum(
    const int* __restrict__ v, int* __restrict__ part, int n)
{
    __shared__ int red[256];
    const int base = blockIdx.x * SCAN_CHUNK;
    int s = 0;
    for (int i = threadIdx.x; i < SCAN_CHUNK; i += 256) {
        int idx = base + i;
        if (idx < n) s += v[idx];
    }
    red[threadIdx.x] = s;
    __syncthreads();
    for (int off = 128; off > 0; off >>= 1) {
        if (threadIdx.x < off) red[threadIdx.x] += red[threadIdx.x + off];
        __syncthreads();
    }
    if (threadIdx.x == 0) part[blockIdx.x] = red[0];
}

__global__ void k_scan_part(int* __restrict__ part, int nparts)
{
    if (threadIdx.x == 0 && blockIdx.x == 0) {
        int run = 0;
        for (int i = 0; i < nparts; ++i) { int v = part[i]; part[i] = run; run += v; }
    }
}

__global__ __launch_bounds__(256) void k_write_off(
    const int* __restrict__ v, const int* __restrict__ part,
    int* __restrict__ off, int n, int total)
{
    __shared__ int lds[256];
    const int tid   = threadIdx.x;
    const int base  = blockIdx.x * SCAN_CHUNK;
    const int tbase = base + tid * 8;
    int c[8];
    int tot = 0;
#pragma unroll
    for (int m = 0; m < 8; ++m) {
        int idx = tbase + m;
        c[m] = (idx < n) ? v[idx] : 0;
        tot += c[m];
    }
    lds[tid] = tot;
    __syncthreads();
    for (int o = 1; o < 256; o <<= 1) {
        int val = (tid >= o) ? lds[tid - o] : 0;
        __syncthreads();
        lds[tid] += val;
        __syncthreads();
    }
    int run = part[blockIdx.x] + lds[tid] - tot;
#pragma unroll
    for (int m = 0; m < 8; ++m) {
        int idx = tbase + m;
        if (idx < n) off[idx] = run;
        run += c[m];
    }
    if (blockIdx.x == 0 && tid == 0) off[n] = total;
}

// ---------------- Pass 3: bin packed edges into tile regions ----------------
__global__ __launch_bounds__(1024) void k_binfill(
    const int* __restrict__ src, const int* __restrict__ dst,
    const int* __restrict__ off, unsigned int* __restrict__ ebuf,
    int n_edges, int NB, int C)
{
    __shared__ int lcur[MAX_NB];
    const int c = blockIdx.x;
    for (int b = threadIdx.x; b < NB; b += 1024)
        lcur[b] = off[b * C + c];
    __syncthreads();
    const int beg = c * CE;
    const int end = min(beg + CE, n_edges);
    for (int e = beg + threadIdx.x; e < end; e += 1024) {
        const int d = dst[e];
        const int b = d >> 8;
        const unsigned int dl = (unsigned int)(d & 255);
        const int pos = atomicAdd(&lcur[b], 1);
        ebuf[pos] = (dl << 17) | (unsigned int)src[e];
    }
}

// ---- Pass 4: per-tile counting sort -> padded eidx + ptrb/ptre ----
__global__ __launch_bounds__(1024) void k_tile_sort(
    const int* __restrict__ off, const unsigned int* __restrict__ ebuf,
    int* __restrict__ eidx, int* __restrict__ ptrb, int* __restrict__ ptre,
    int n_nodes, int NB, int C, int n_edges)
{
    __shared__ int hist[TILE_NODES];
    __shared__ int phist[TILE_NODES];
    __shared__ int scan[TILE_NODES];
    __shared__ int cur[TILE_NODES];
    const int t = blockIdx.x;
    const int beg = off[t * C];
    const int end = (t + 1 < NB) ? off[(t + 1) * C] : n_edges;
    const int tb  = ((beg + 3) & ~3) + 1024 * t;      // padded, 4-aligned base
    const int node_base = t * TILE_NODES;
    const int n_valid = min(TILE_NODES, n_nodes - node_base);

    if (threadIdx.x < TILE_NODES) hist[threadIdx.x] = 0;
    __syncthreads();
    for (int e = beg + threadIdx.x; e < end; e += 1024)
        atomicAdd(&hist[ebuf[e] >> 17], 1);
    __syncthreads();
    if (threadIdx.x < TILE_NODES) {
        const int ph = (hist[threadIdx.x] + 3) & ~3;
        phist[threadIdx.x] = ph;
        scan[threadIdx.x]  = ph;
    }
    __syncthreads();
    for (int o = 1; o < TILE_NODES; o <<= 1) {
        int v = 0;
        if (threadIdx.x < TILE_NODES && threadIdx.x >= o) v = scan[threadIdx.x - o];
        __syncthreads();
        if (threadIdx.x < TILE_NODES) scan[threadIdx.x] += v;
        __syncthreads();
    }
    if (threadIdx.x < TILE_NODES) {
        const int ex = scan[threadIdx.x] - phist[threadIdx.x];   // exclusive
        cur[threadIdx.x] = ex;
        if (threadIdx.x < n_valid) {
            ptrb[node_base + threadIdx.x] = tb + ex;
            ptre[node_base + threadIdx.x] = tb + ex + phist[threadIdx.x];
        }
    }
    __syncthreads();
    for (int e = beg + threadIdx.x; e < end; e += 1024) {
        const unsigned int v = ebuf[e];
        const int dl = (int)(v >> 17);
        const int pos = tb + atomicAdd(&cur[dl], 1);
        eidx[pos] = (int)(v & 0x1FFFFu);
    }
    __syncthreads();
    if (threadIdx.x < n_valid) {
        int p  = tb + cur[threadIdx.x];
        const int pe = tb + scan[threadIdx.x];
        for (; p < pe; ++p) eidx[p] = SENT;
    }
}

// ---- Weight prep: fragment-order f16 buffers (once per call) ----
// Layer0: 16 frags (mat2 x coltile2 x kchunk4); layers 1-3: 4 frags each.
// Fragment f, lane l holds W[k = c*32 + (l>>4)*8 + j][n = 16t + (l&15)], j=0..7.
__global__ __launch_bounds__(64) void k_wprep(
    const float* __restrict__ Wn0, const float* __restrict__ Ws0,
    const float* __restrict__ Wn, const float* __restrict__ Ws,
    unsigned char* __restrict__ wf0, unsigned char* __restrict__ wfl)
{
    const int f = blockIdx.x;
    const int l = threadIdx.x;
    const int n15 = l & 15, quad = l >> 4;
    unsigned u[4];
    if (f < 16) {
        const int mat = f >> 3, t = (f >> 2) & 1, c = f & 3;
        const float* W = mat ? Ws0 : Wn0;
        const int n = 16 * t + n15;
#pragma unroll
        for (int p = 0; p < 4; ++p) {
            const int k = c * 32 + quad * 8 + 2 * p;
            u[p] = packh2(W[k * 32 + n], W[(k + 1) * 32 + n]);
        }
        *(uint4*)(wf0 + f * 1024 + l * 16) = make_uint4(u[0], u[1], u[2], u[3]);
    } else {
        const int g = f - 16;                     // 0..11
        const int L = g >> 2, ff = g & 3;
        const int mat = ff >> 1, t = ff & 1;
        const float* W = (mat ? Ws : Wn) + L * 1024;
        const int n = 16 * t + n15;
#pragma unroll
        for (int p = 0; p < 4; ++p) {
            const int k = quad * 8 + 2 * p;
            u[p] = packh2(W[k * 32 + n], W[(k + 1) * 32 + n]);
        }
        *(uint4*)(wfl + (size_t)g * 1024 + l * 16) = make_uint4(u[0], u[1], u[2], u[3]);
    }
}

// ---------------- Layer 0 (MFMA): A(fp8) = x@Wn0 ; B = x@Ws0 + bn0 ----------------
// 64 nodes/block (16 per wave). x staged f16: row stride 256B, 64B chunk at
// physical (c ^ (row&1)) -> bank-balanced b128 A-frag reads.
__global__ __launch_bounds__(256, 4) void k_layer0(
    const float* __restrict__ x, const unsigned char* __restrict__ wf0,
    const float* __restrict__ bn0,
    unsigned char* __restrict__ Ab, float* __restrict__ B, int n_nodes)
{
    __shared__ unsigned char sxh[64 * 256];
    const int tile = blockIdx.x * 64;
    {
        const float4* s4 = (const float4*)(x + (size_t)tile * 128);
        const int lim = (n_nodes - tile) * 32;   // float4 count
#pragma unroll
        for (int m = 0; m < 8; ++m) {
            int i = threadIdx.x + m * 256;
            if (i < lim) {
                float4 v = s4[i];
                const int row = i >> 5, kq = i & 31;
                const int c = kq >> 3;
                unsigned* wp = (unsigned*)(sxh + row * 256 +
                                           ((c ^ (row & 1)) * 64) + (kq & 7) * 8);
                wp[0] = packh2(v.x, v.y);
                wp[1] = packh2(v.z, v.w);
            }
        }
    }
    const int l = threadIdx.x & 63;
    const int w = threadIdx.x >> 6;
    const int n15 = l & 15, quad = l >> 4;
    UF bf[16];
#pragma unroll
    for (int f = 0; f < 16; ++f)
        bf[f].u = *(const uint4*)(wf0 + f * 1024 + l * 16);
    const float bias0 = bn0[n15];
    const float bias1 = bn0[16 + n15];
    __syncthreads();

    f32x4v aN0 = {0.f, 0.f, 0.f, 0.f}, aN1 = {0.f, 0.f, 0.f, 0.f};
    f32x4v aS0 = {bias0, bias0, bias0, bias0};
    f32x4v aS1 = {bias1, bias1, bias1, bias1};
    const int row = w * 16 + n15;
#pragma unroll
    for (int c = 0; c < 4; ++c) {
        UF a;
        a.u = *(const uint4*)(sxh + row * 256 + ((c ^ (row & 1)) * 64) + quad * 16);
        aN0 = __builtin_amdgcn_mfma_f32_16x16x32_f16(a.h, bf[c].h,      aN0, 0, 0, 0);
        aN1 = __builtin_amdgcn_mfma_f32_16x16x32_f16(a.h, bf[4 + c].h,  aN1, 0, 0, 0);
        aS0 = __builtin_amdgcn_mfma_f32_16x16x32_f16(a.h, bf[8 + c].h,  aS0, 0, 0, 0);
        aS1 = __builtin_amdgcn_mfma_f32_16x16x32_f16(a.h, bf[12 + c].h, aS1, 0, 0, 0);
    }
#pragma unroll
    for (int r = 0; r < 4; ++r) {
        const int node = tile + w * 16 + quad * 4 + r;
        if (node < n_nodes) {
            B[(size_t)node * 32 + n15]      = aS0[r];
            B[(size_t)node * 32 + 16 + n15] = aS1[r];
            Ab[(size_t)node * 32 + n15]      = f2fp8(aN0[r]);
            Ab[(size_t)node * 32 + 16 + n15] = f2fp8(aN1[r]);
        }
    }
}

// ------- Layers 1..3 (MFMA, in-place): A(fp8) = relu(B)@Wn ; B = relu(B)@Ws + bn -------
__global__ __launch_bounds__(256, 4) void k_layer(
    float* HB, const unsigned char* __restrict__ wfl,   // this layer's 4 frags
    const float* __restrict__ bnv,
    unsigned char* __restrict__ Ab, int n_nodes)
{
    __shared__ unsigned char shh[64 * 64];   // f16 rows, 64 B each
    const int tile = blockIdx.x * 64;
    {
        const float4* s4 = (const float4*)(HB + (size_t)tile * 32);
        const int lim = (n_nodes - tile) * 8;    // float4 count
#pragma unroll
        for (int m = 0; m < 2; ++m) {
            int i = threadIdx.x + m * 256;
            if (i < lim) {
                float4 v = s4[i];
                v.x = fmaxf(v.x, 0.f); v.y = fmaxf(v.y, 0.f);
                v.z = fmaxf(v.z, 0.f); v.w = fmaxf(v.w, 0.f);
                const int row = i >> 3, q = i & 7;
                unsigned* wp = (unsigned*)(shh + row * 64 + q * 8);
                wp[0] = packh2(v.x, v.y);
                wp[1] = packh2(v.z, v.w);
            }
        }
    }
    const int l = threadIdx.x & 63;
    const int w = threadIdx.x >> 6;
    const int n15 = l & 15, quad = l >> 4;
    UF b0, b1, b2, b3;
    b0.u = *(const uint4*)(wfl + 0 * 1024 + l * 16);   // Wn cols 0-15
    b1.u = *(const uint4*)(wfl + 1 * 1024 + l * 16);   // Wn cols 16-31
    b2.u = *(const uint4*)(wfl + 2 * 1024 + l * 16);   // Ws cols 0-15
    b3.u = *(const uint4*)(wfl + 3 * 1024 + l * 16);   // Ws cols 16-31
    const float bias0 = bnv[n15];
    const float bias1 = bnv[16 + n15];
    __syncthreads();

    const int row = w * 16 + n15;
    UF a;
    a.u = *(const uint4*)(shh + row * 64 + quad * 16);
    f32x4v aN0 = {0.f, 0.f, 0.f, 0.f}, aN1 = {0.f, 0.f, 0.f, 0.f};
    f32x4v aS0 = {bias0, bias0, bias0, bias0};
    f32x4v aS1 = {bias1, bias1, bias1, bias1};
    aN0 = __builtin_amdgcn_mfma_f32_16x16x32_f16(a.h, b0.h, aN0, 0, 0, 0);
    aN1 = __builtin_amdgcn_mfma_f32_16x16x32_f16(a.h, b1.h, aN1, 0, 0, 0);
    aS0 = __builtin_amdgcn_mfma_f32_16x16x32_f16(a.h, b2.h, aS0, 0, 0, 0);
    aS1 = __builtin_amdgcn_mfma_f32_16x16x32_f16(a.h, b3.h, aS1, 0, 0, 0);
#pragma unroll
    for (int r = 0; r < 4; ++r) {
        const int node = tile + w * 16 + quad * 4 + r;
        if (node < n_nodes) {
            HB[(size_t)node * 32 + n15]      = aS0[r];
            HB[(size_t)node * 32 + 16 + n15] = aS1[r];
            Ab[(size_t)node * 32 + n15]      = f2fp8(aN0[r]);
            Ab[(size_t)node * 32 + 16 + n15] = f2fp8(aN1[r]);
        }
    }
}

// ------------- Aggregation: B[n] += sum_{e in padded CSR[n]} A_fp8[eidx[e]] -------------
__global__ __launch_bounds__(256) void k_agg3(
    const int* __restrict__ ptrb, const int* __restrict__ ptre,
    const int* __restrict__ eidx,
    const unsigned char* __restrict__ Ab, float* __restrict__ B, int n_nodes)
{
    const int g    = blockIdx.x * 64 + (threadIdx.x >> 2);
    const int lane = threadIdx.x & 3;
    if (g >= n_nodes) return;
    const int beg = ptrb[g];
    const int end = ptre[g];
    const uint2* __restrict__ A2 = (const uint2*)Ab;   // 8B = 8 fp8
    const int4* __restrict__ E4 = (const int4*)eidx;   // beg is 4-aligned
    float4* B4 = (float4*)B;

    float4 a0 = B4[(size_t)g * 8 + lane * 2 + 0];
    float4 a1 = B4[(size_t)g * 8 + lane * 2 + 1];
    int e4 = beg >> 2;
    const int n4 = end >> 2;
    for (; e4 + 4 <= n4; e4 += 4) {
        const int4 q0 = E4[e4 + 0];
        const int4 q1 = E4[e4 + 1];
        const int4 q2 = E4[e4 + 2];
        const int4 q3 = E4[e4 + 3];
        uint2 rw;
        rw = A2[(size_t)q0.x * 4 + lane]; acc8_fp8(rw.x, rw.y, a0, a1);
        rw = A2[(size_t)q0.y * 4 + lane]; acc8_fp8(rw.x, rw.y, a0, a1);
        rw = A2[(size_t)q0.z * 4 + lane]; acc8_fp8(rw.x, rw.y, a0, a1);
        rw = A2[(size_t)q0.w * 4 + lane]; acc8_fp8(rw.x, rw.y, a0, a1);
        rw = A2[(size_t)q1.x * 4 + lane]; acc8_fp8(rw.x, rw.y, a0, a1);
        rw = A2[(size_t)q1.y * 4 + lane]; acc8_fp8(rw.x, rw.y, a0, a1);
        rw = A2[(size_t)q1.z * 4 + lane]; acc8_fp8(rw.x, rw.y, a0, a1);
        rw = A2[(size_t)q1.w * 4 + lane]; acc8_fp8(rw.x, rw.y, a0, a1);
        rw = A2[(size_t)q2.x * 4 + lane]; acc8_fp8(rw.x, rw.y, a0, a1);
        rw = A2[(size_t)q2.y * 4 + lane]; acc8_fp8(rw.x, rw.y, a0, a1);
        rw = A2[(size_t)q2.z * 4 + lane]; acc8_fp8(rw.x, rw.y, a0, a1);
        rw = A2[(size_t)q2.w * 4 + lane]; acc8_fp8(rw.x, rw.y, a0, a1);
        rw = A2[(size_t)q3.x * 4 + lane]; acc8_fp8(rw.x, rw.y, a0, a1);
        rw = A2[(size_t)q3.y * 4 + lane]; acc8_fp8(rw.x, rw.y, a0, a1);
        rw = A2[(size_t)q3.z * 4 + lane]; acc8_fp8(rw.x, rw.y, a0, a1);
        rw = A2[(size_t)q3.w * 4 + lane]; acc8_fp8(rw.x, rw.y, a0, a1);
    }
    for (; e4 < n4; ++e4) {
        const int4 q = E4[e4];
        uint2 rw;
        rw = A2[(size_t)q.x * 4 + lane]; acc8_fp8(rw.x, rw.y, a0, a1);
        rw = A2[(size_t)q.y * 4 + lane]; acc8_fp8(rw.x, rw.y, a0, a1);
        rw = A2[(size_t)q.z * 4 + lane]; acc8_fp8(rw.x, rw.y, a0, a1);
        rw = A2[(size_t)q.w * 4 + lane]; acc8_fp8(rw.x, rw.y, a0, a1);
    }
    B4[(size_t)g * 8 + lane * 2 + 0] = a0;
    B4[(size_t)g * 8 + lane * 2 + 1] = a1;
}

// ---------------- Zero helper ----------------
__global__ __launch_bounds__(256) void k_zero_f(float* __restrict__ p, int n)
{
    int i = blockIdx.x * 256 + threadIdx.x;
    if (i < n) p[i] = 0.f;
}

// ---------------- Node-parallel per-graph sum pool ----------------
__global__ __launch_bounds__(256) void k_pool1(
    const float* __restrict__ H, const int* __restrict__ gids,
    float* __restrict__ hg, int n_nodes)
{
    const int base = blockIdx.x * 128;
    const int lim  = min(base + 128, n_nodes);
    const int j = threadIdx.x & 31;
    const int r = threadIdx.x >> 5;

    int curg = -1;
    float acc = 0.f;
    for (int n = base + r; n < lim; n += 8) {
        const int g = gids[n];
        const float v = fmaxf(H[(size_t)n * 32 + j], 0.f);
        if (g != curg) {
            if (curg >= 0) atomicAdd(&hg[curg * 32 + j], acc);
            curg = g;
            acc = v;
        } else {
            acc += v;
        }
    }
    if (curg >= 0) atomicAdd(&hg[curg * 32 + j], acc);
}

// ---------------- FC head + softmax ----------------
__global__ __launch_bounds__(64) void k_head(
    const float* __restrict__ hg,
    const float* __restrict__ Wfc1, const float* __restrict__ bfc1,
    const float* __restrict__ Wout, const float* __restrict__ bout,
    float* __restrict__ out, int n_graphs)
{
    const int g = blockIdx.x * blockDim.x + threadIdx.x;
    if (g >= n_graphs) return;
    float h[32];
#pragma unroll
    for (int k = 0; k < 32; ++k) h[k] = hg[g * 32 + k];
    float z[8];
#pragma unroll
    for (int m = 0; m < 8; ++m) {
        float a = bfc1[m];
#pragma unroll
        for (int k = 0; k < 32; ++k) a += h[k] * Wfc1[k * 8 + m];
        z[m] = fmaxf(a, 0.f);
    }
    float o[4];
#pragma unroll
    for (int q = 0; q < 4; ++q) {
        float a = bout[q];
#pragma unroll
        for (int m = 0; m < 8; ++m) a += z[m] * Wout[m * 4 + q];
        o[q] = fmaxf(a, 0.f);
    }
    const float mx = fmaxf(fmaxf(o[0], o[1]), fmaxf(o[2], o[3]));
    const float e0 = expf(o[0] - mx), e1 = expf(o[1] - mx);
    const float e2 = expf(o[2] - mx), e3 = expf(o[3] - mx);
    const float inv = 1.f / (e0 + e1 + e2 + e3);
    out[g * 4 + 0] = e0 * inv;
    out[g * 4 + 1] = e1 * inv;
    out[g * 4 + 2] = e2 * inv;
    out[g * 4 + 3] = e3 * inv;
}

extern "C" void kernel_launch(void* const* d_in, const int* in_sizes, int n_in,
                              void* d_out, int out_size, void* d_ws, size_t ws_size,
                              hipStream_t stream)
{
    const float* x    = (const float*)d_in[0];
    const float* Wn0  = (const float*)d_in[1];
    const float* bn0  = (const float*)d_in[2];
    const float* Ws0  = (const float*)d_in[3];
    const float* Wn   = (const float*)d_in[4];   // [3,32,32]
    const float* bn   = (const float*)d_in[5];   // [3,32]
    const float* Ws   = (const float*)d_in[6];   // [3,32,32]
    const float* Wfc1 = (const float*)d_in[7];
    const float* bfc1 = (const float*)d_in[8];
    const float* Wout = (const float*)d_in[9];
    const float* bout = (const float*)d_in[10];
    const int*   src  = (const int*)d_in[11];
    const int*   dst  = (const int*)d_in[12];
    const int*   gids = (const int*)d_in[13];

    const int n_nodes  = in_sizes[0] / 128;
    const int n_edges  = in_sizes[11];
    const int n_graphs = out_size / 4;
    const size_t N32 = (size_t)n_nodes * 32;
    const size_t AB_ROWS = 131072;

    const int NB = (n_nodes + TILE_NODES - 1) / TILE_NODES;
    const int C  = (n_edges + CE - 1) / CE;
    const int n_off = NB * C;

    char* p = (char*)d_ws;
    auto alloc = [&](size_t bytes) {
        char* r = p; p += (bytes + 255) & ~(size_t)255; return r;
    };
    unsigned char* Ab  = (unsigned char*)alloc(AB_ROWS * 32);
    float* B           = (float*)alloc(N32 * 4);
    float* hg          = (float*)alloc((size_t)n_graphs * 32 * 4);
    int* histT         = (int*)alloc((size_t)n_off * 4);
    int* off           = (int*)alloc(((size_t)n_off + 1) * 4);
    int* part          = (int*)alloc(256 * 4);
    int* ptrb          = (int*)alloc((size_t)n_nodes * 4);
    int* ptre          = (int*)alloc((size_t)n_nodes * 4);
    unsigned char* wf0 = (unsigned char*)alloc(16 * 1024);
    unsigned char* wfl = (unsigned char*)alloc(12 * 1024);
    unsigned int* ebuf = (unsigned int*)alloc((size_t)n_edges * 4);
    int* eidx          = (int*)alloc(((size_t)n_edges + 1024 * (size_t)NB + 4) * 4);

    const int nparts = (n_off + SCAN_CHUNK - 1) / SCAN_CHUNK;

    // ---- edge sort + weight prep (once per call) ----
    k_hist2<<<C, 1024, 0, stream>>>(dst, histT, n_edges, NB, C);
    k_chunk_sum<<<nparts, 256, 0, stream>>>(histT, part, n_off);
    k_scan_part<<<1, 64, 0, stream>>>(part, nparts);
    k_write_off<<<nparts, 256, 0, stream>>>(histT, part, off, n_off, n_edges);
    k_binfill<<<C, 1024, 0, stream>>>(src, dst, off, ebuf, n_edges, NB, C);
    k_tile_sort<<<NB, 1024, 0, stream>>>(off, ebuf, eidx, ptrb, ptre,
                                         n_nodes, NB, C, n_edges);
    k_wprep<<<28, 64, 0, stream>>>(Wn0, Ws0, Wn, Ws, wf0, wfl);
    k_zero_f<<<1, 256, 0, stream>>>((float*)(Ab + (size_t)SENT * 32), 8);

    const int mblocks = (n_nodes + 63) / 64;
    const int ablocks = (n_nodes + 63) / 64;

    // ---- Layer 0 ----
    k_layer0<<<mblocks, 256, 0, stream>>>(x, wf0, bn0, Ab, B, n_nodes);
    k_agg3<<<ablocks, 256, 0, stream>>>(ptrb, ptre, eidx, Ab, B, n_nodes);

    // ---- Layers 1..3 (in-place on B) ----
    for (int l = 0; l < 3; ++l) {
        k_layer<<<mblocks, 256, 0, stream>>>(B, wfl + (size_t)l * 4096,
                                             bn + l * 32, Ab, n_nodes);
        k_agg3<<<ablocks, 256, 0, stream>>>(ptrb, ptre, eidx, Ab, B, n_nodes);
    }

    // ---- Pool + head ----
    k_zero_f<<<(n_graphs * 32 + 255) / 256, 256, 0, stream>>>(hg, n_graphs * 32);
    k_pool1<<<(n_nodes + 127) / 128, 256, 0, stream>>>(B, gids, hg, n_nodes);
    k_head<<<(n_graphs + 63) / 64, 64, 0, stream>>>(hg, Wfc1, bfc1, Wout, bout,
                                                    (float*)d_out, n_graphs);
}